// Round 1
// baseline (5765.767 us; speedup 1.0000x reference)
//
#include <hip/hip_runtime.h>
#include <math.h>

#define N_NODES 50000
#define N_EDGES 600000
#define D 128
#define N_GRAPHS 512
#define N_CLASSES 10
#define N_LAYERS 4

// ---------------- utility: zero fill (float4 granularity) ----------------
__global__ __launch_bounds__(256) void fill_zero4(float4* p, int n4) {
    int i = blockIdx.x * 256 + threadIdx.x;
    if (i < n4) p[i] = make_float4(0.f, 0.f, 0.f, 0.f);
}

// ---------------- transpose Ws: WsT[l][j][k] = Ws[l][k][j] ----------------
__global__ __launch_bounds__(256) void transpose_ws(const float* __restrict__ Ws,
                                                    float* __restrict__ WsT) {
    int idx = blockIdx.x * 256 + threadIdx.x;     // 4*128*128 = 65536 total
    int l = idx >> 14;
    int rem = idx & 16383;
    int j = rem >> 7;
    int k = rem & 127;
    WsT[idx] = Ws[(l << 14) + (k << 7) + j];
}

// ---------------- GEMM: C[i,j] = sum_k A[i,k] * W[j,k] (+bias) ----------------
// MODE 0: C[i*J + j] = acc + bias[j]           (bias may be null)
// MODE 1: (GRU gh pass, J==384)
//         j < 256 : C[i*384 + j] += acc + bias[j]     (sum into gi r/z parts)
//         j >= 256: C2[i*128 + (j-256)] = acc + bias[j]  (h_n)
template <int MODE>
__global__ __launch_bounds__(256) void gemm_nt(const float* __restrict__ A,
                                               const float* __restrict__ W,
                                               const float* __restrict__ bias,
                                               float* __restrict__ C,
                                               float* __restrict__ C2,
                                               int M, int J) {
    __shared__ float As[64][132];
    __shared__ float Bs[64][132];
    int i0 = blockIdx.x * 64;
    int j0 = blockIdx.y * 64;
    int tid = threadIdx.x;

    // stage tiles: 64 rows x 128 cols each
    {
        int r = tid >> 5;
        int c4 = (tid & 31) * 4;
        #pragma unroll
        for (int it = 0; it < 8; ++it, r += 8) {
            int gi_ = i0 + r;
            float4 v = make_float4(0.f, 0.f, 0.f, 0.f);
            if (gi_ < M) v = *(const float4*)(A + (size_t)gi_ * D + c4);
            *(float4*)&As[r][c4] = v;
            float4 w = *(const float4*)(W + (size_t)(j0 + r) * D + c4);
            *(float4*)&Bs[r][c4] = w;
        }
    }
    __syncthreads();

    int tr = (tid >> 4) * 4;   // row offset in tile
    int tc = (tid & 15) * 4;   // col offset in tile
    float acc[4][4] = {};

    for (int k = 0; k < D; k += 4) {
        float4 a[4], b[4];
        #pragma unroll
        for (int p = 0; p < 4; ++p) a[p] = *(float4*)&As[tr + p][k];
        #pragma unroll
        for (int q = 0; q < 4; ++q) b[q] = *(float4*)&Bs[tc + q][k];
        #pragma unroll
        for (int p = 0; p < 4; ++p)
            #pragma unroll
            for (int q = 0; q < 4; ++q)
                acc[p][q] += a[p].x * b[q].x + a[p].y * b[q].y +
                             a[p].z * b[q].z + a[p].w * b[q].w;
    }

    #pragma unroll
    for (int p = 0; p < 4; ++p) {
        int i = i0 + tr + p;
        if (i >= M) continue;
        #pragma unroll
        for (int q = 0; q < 4; ++q) {
            int j = j0 + tc + q;
            float v = acc[p][q] + (bias ? bias[j] : 0.f);
            if (MODE == 0) {
                C[(size_t)i * J + j] = v;
            } else {
                if (j < 256) C[(size_t)i * 384 + j] += v;
                else         C2[(size_t)i * 128 + (j - 256)] = v;
            }
        }
    }
}

// ---------------- scatter: agg[dst[e]] += m[src[e]] ----------------
__global__ __launch_bounds__(256) void scatter_add(const float* __restrict__ m,
                                                   const int* __restrict__ src,
                                                   const int* __restrict__ dst,
                                                   float* __restrict__ agg) {
    int idx = blockIdx.x * 256 + threadIdx.x;   // E*32 threads
    int e = idx >> 5;
    int c4 = (idx & 31) * 4;
    if (e >= N_EDGES) return;
    int s = src[e];
    int d = dst[e];
    float4 v = *(const float4*)(m + (size_t)s * D + c4);
    float* o = agg + (size_t)d * D + c4;
    atomicAdd(o + 0, v.x);
    atomicAdd(o + 1, v.y);
    atomicAdd(o + 2, v.z);
    atomicAdd(o + 3, v.w);
}

// ---------------- GRU gates + relu, h updated in place ----------------
__global__ __launch_bounds__(256) void gru_gates(const float* __restrict__ gi,
                                                 const float* __restrict__ hn,
                                                 float* __restrict__ h) {
    int idx = blockIdx.x * 256 + threadIdx.x;   // N*D
    if (idx >= N_NODES * D) return;
    int i = idx >> 7;
    int c = idx & 127;
    size_t base = (size_t)i * 384;
    float g_r = gi[base + c];         // i_r + h_r (already summed)
    float g_z = gi[base + 128 + c];   // i_z + h_z
    float i_n = gi[base + 256 + c];
    float h_n = hn[(size_t)i * 128 + c];
    float r = 1.f / (1.f + expf(-g_r));
    float z = 1.f / (1.f + expf(-g_z));
    float n = tanhf(i_n + r * h_n);
    float h_old = h[idx];
    float h_new = (1.f - z) * n + z * h_old;
    h[idx] = h_new > 0.f ? h_new : 0.f;
}

// ---------------- pooling: sums + counts via atomics ----------------
__global__ __launch_bounds__(256) void pool_add(const float* __restrict__ h,
                                                const int* __restrict__ batch,
                                                float* __restrict__ hg,
                                                float* __restrict__ cnt) {
    int idx = blockIdx.x * 256 + threadIdx.x;   // N*32
    int i = idx >> 5;
    int c4 = (idx & 31) * 4;
    if (i >= N_NODES) return;
    int g = batch[i];
    float4 v = *(const float4*)(h + (size_t)i * D + c4);
    float* o = hg + (size_t)g * D + c4;
    atomicAdd(o + 0, v.x);
    atomicAdd(o + 1, v.y);
    atomicAdd(o + 2, v.z);
    atomicAdd(o + 3, v.w);
    if (c4 == 0) atomicAdd(&cnt[g], 1.0f);
}

__global__ __launch_bounds__(256) void pool_norm(float* __restrict__ hg,
                                                 const float* __restrict__ cnt) {
    int idx = blockIdx.x * 256 + threadIdx.x;   // G*D
    if (idx >= N_GRAPHS * D) return;
    int g = idx >> 7;
    hg[idx] /= fmaxf(cnt[g], 1.f);
}

// ---------------- fc1 + elu ----------------
__global__ __launch_bounds__(128) void fc1_elu(const float* __restrict__ hg,
                                               const float* __restrict__ w,
                                               const float* __restrict__ b,
                                               float* __restrict__ z) {
    __shared__ float row[128];
    int g = blockIdx.x;
    int j = threadIdx.x;
    row[j] = hg[(size_t)g * 128 + j];
    __syncthreads();
    float acc = b[j];
    const float* wr = w + (size_t)j * 128;
    #pragma unroll 4
    for (int k = 0; k < 128; ++k) acc += row[k] * wr[k];
    z[(size_t)g * 128 + j] = acc > 0.f ? acc : (expf(acc) - 1.f);
}

// ---------------- fc2 ----------------
__global__ __launch_bounds__(64) void fc2_k(const float* __restrict__ z,
                                            const float* __restrict__ w,
                                            const float* __restrict__ b,
                                            float* __restrict__ logits) {
    __shared__ float row[128];
    int g = blockIdx.x;
    int t = threadIdx.x;
    row[t] = z[(size_t)g * 128 + t];
    row[t + 64] = z[(size_t)g * 128 + 64 + t];
    __syncthreads();
    if (t < N_CLASSES) {
        float acc = b[t];
        const float* wr = w + (size_t)t * 128;
        #pragma unroll 4
        for (int k = 0; k < 128; ++k) acc += row[k] * wr[k];
        logits[(size_t)g * N_CLASSES + t] = acc;
    }
}

// ---------------- log_softmax over axis 0 (graphs), per class ----------------
__global__ __launch_bounds__(512) void logsoftmax_axis0(const float* __restrict__ logits,
                                                        float* __restrict__ out) {
    __shared__ float red[512];
    int c = blockIdx.x;          // class
    int g = threadIdx.x;         // graph
    float x = logits[(size_t)g * N_CLASSES + c];
    red[g] = x;
    __syncthreads();
    for (int s = 256; s > 0; s >>= 1) {
        if (g < s) red[g] = fmaxf(red[g], red[g + s]);
        __syncthreads();
    }
    float mx = red[0];
    __syncthreads();
    red[g] = expf(x - mx);
    __syncthreads();
    for (int s = 256; s > 0; s >>= 1) {
        if (g < s) red[g] += red[g + s];
        __syncthreads();
    }
    float lse = mx + logf(red[0]);
    out[(size_t)g * N_CLASSES + c] = x - lse;
}

// ---------------- launch ----------------
extern "C" void kernel_launch(void* const* d_in, const int* in_sizes, int n_in,
                              void* d_out, int out_size, void* d_ws, size_t ws_size,
                              hipStream_t stream) {
    const float* h_in   = (const float*)d_in[0];
    const int*   eidx   = (const int*)d_in[1];
    // d_in[2] = edge_attr (unused by reference)
    const int*   batch  = (const int*)d_in[3];
    const float* Ws     = (const float*)d_in[4];
    const float* W_ih   = (const float*)d_in[5];
    const float* W_hh   = (const float*)d_in[6];
    const float* b_ih   = (const float*)d_in[7];
    const float* b_hh   = (const float*)d_in[8];
    const float* fc1_w  = (const float*)d_in[9];
    const float* fc1_b  = (const float*)d_in[10];
    const float* fc2_w  = (const float*)d_in[11];
    const float* fc2_b  = (const float*)d_in[12];
    float* out = (float*)d_out;

    char* ws = (char*)d_ws;
    size_t off = 0;
    auto alloc = [&](size_t bytes) {
        void* p = ws + off;
        off += (bytes + 255) & ~(size_t)255;
        return p;
    };
    float* h    = (float*)alloc((size_t)N_NODES * D * 4);       // current node state
    float* m    = (float*)alloc((size_t)N_NODES * D * 4);       // m, reused as h_n
    float* agg  = (float*)alloc((size_t)N_NODES * D * 4);
    float* gi   = (float*)alloc((size_t)N_NODES * 384 * 4);
    float* WsT  = (float*)alloc((size_t)N_LAYERS * D * D * 4);
    float* hg   = (float*)alloc((size_t)N_GRAPHS * D * 4);
    float* cnt  = (float*)alloc((size_t)N_GRAPHS * 4);
    float* zb   = (float*)alloc((size_t)N_GRAPHS * D * 4);
    float* lgts = (float*)alloc((size_t)N_GRAPHS * N_CLASSES * 4);

    const int* src = eidx;
    const int* dst = eidx + N_EDGES;

    hipMemcpyAsync(h, h_in, (size_t)N_NODES * D * 4, hipMemcpyDeviceToDevice, stream);
    transpose_ws<<<256, 256, 0, stream>>>(Ws, WsT);

    const int mtiles = (N_NODES + 63) / 64;   // 782
    for (int l = 0; l < N_LAYERS; ++l) {
        // m = h @ Ws[l]
        gemm_nt<0><<<dim3(mtiles, 2), 256, 0, stream>>>(h, WsT + (size_t)l * D * D,
                                                        nullptr, m, nullptr, N_NODES, 128);
        // agg = scatter_add(m[src] -> dst)
        fill_zero4<<<(N_NODES * D / 4 + 255) / 256, 256, 0, stream>>>((float4*)agg, N_NODES * D / 4);
        scatter_add<<<(N_EDGES * 32) / 256, 256, 0, stream>>>(m, src, dst, agg);
        // gi = agg @ W_ih[l]^T + b_ih[l]
        gemm_nt<0><<<dim3(mtiles, 6), 256, 0, stream>>>(agg, W_ih + (size_t)l * 384 * D,
                                                        b_ih + (size_t)l * 384, gi, nullptr,
                                                        N_NODES, 384);
        // gh pass: gi[:, :256] += h@W_hh^T + b_hh ; hn = last 128 cols
        gemm_nt<1><<<dim3(mtiles, 6), 256, 0, stream>>>(h, W_hh + (size_t)l * 384 * D,
                                                        b_hh + (size_t)l * 384, gi, m,
                                                        N_NODES, 384);
        gru_gates<<<(N_NODES * D + 255) / 256, 256, 0, stream>>>(gi, m, h);
    }

    // global mean pool
    fill_zero4<<<(N_GRAPHS * D / 4 + 255) / 256, 256, 0, stream>>>((float4*)hg, N_GRAPHS * D / 4);
    fill_zero4<<<1, 256, 0, stream>>>((float4*)cnt, N_GRAPHS / 4);
    pool_add<<<(N_NODES * 32) / 256, 256, 0, stream>>>(h, batch, hg, cnt);
    pool_norm<<<(N_GRAPHS * D + 255) / 256, 256, 0, stream>>>(hg, cnt);

    // readout
    fc1_elu<<<N_GRAPHS, 128, 0, stream>>>(hg, fc1_w, fc1_b, zb);
    fc2_k<<<N_GRAPHS, 64, 0, stream>>>(zb, fc2_w, fc2_b, lgts);
    logsoftmax_axis0<<<N_CLASSES, 512, 0, stream>>>(lgts, out);
}

// Round 2
// 1942.767 us; speedup vs baseline: 2.9678x; 2.9678x over previous
//
#include <hip/hip_runtime.h>
#include <math.h>

#define N_NODES 50000
#define N_EDGES 600000
#define D 128
#define N_GRAPHS 512
#define N_CLASSES 10
#define N_LAYERS 4

// ---------------- utility: zero fill (float4 granularity) ----------------
__global__ __launch_bounds__(256) void fill_zero4(float4* p, int n4) {
    int i = blockIdx.x * 256 + threadIdx.x;
    if (i < n4) p[i] = make_float4(0.f, 0.f, 0.f, 0.f);
}

// ---------------- transpose Ws: WsT[l][j][k] = Ws[l][k][j] ----------------
__global__ __launch_bounds__(256) void transpose_ws(const float* __restrict__ Ws,
                                                    float* __restrict__ WsT) {
    int idx = blockIdx.x * 256 + threadIdx.x;     // 4*128*128 = 65536 total
    int l = idx >> 14;
    int rem = idx & 16383;
    int j = rem >> 7;
    int k = rem & 127;
    WsT[idx] = Ws[(l << 14) + (k << 7) + j];
}

// ---------------- CSR build: histogram of dst ----------------
__global__ __launch_bounds__(256) void hist_dst(const int* __restrict__ dst,
                                                int* __restrict__ deg) {
    int e = blockIdx.x * 256 + threadIdx.x;
    if (e < N_EDGES) atomicAdd(&deg[dst[e]], 1);
}

// ---------------- CSR build: exclusive scan (single block) ----------------
__global__ __launch_bounds__(1024) void scan_deg(const int* __restrict__ deg,
                                                 int* __restrict__ row_ptr,
                                                 int* __restrict__ pos) {
    __shared__ int part[1024];
    const int CHUNK = (N_NODES + 1023) / 1024;   // 49
    int t = threadIdx.x;
    int start = t * CHUNK;
    int end = min(start + CHUNK, N_NODES);
    int s = 0;
    for (int i = start; i < end; ++i) s += deg[i];
    part[t] = s;
    __syncthreads();
    // Hillis-Steele inclusive scan over 1024 partials
    for (int off = 1; off < 1024; off <<= 1) {
        int v = (t >= off) ? part[t - off] : 0;
        __syncthreads();
        part[t] += v;
        __syncthreads();
    }
    int run = (t == 0) ? 0 : part[t - 1];
    for (int i = start; i < end; ++i) {
        row_ptr[i] = run;
        pos[i] = run;
        run += deg[i];
    }
    if (t == 1023) row_ptr[N_NODES] = part[1023];
}

// ---------------- CSR build: place edges ----------------
__global__ __launch_bounds__(256) void fill_csr(const int* __restrict__ src,
                                                const int* __restrict__ dst,
                                                int* __restrict__ pos,
                                                int* __restrict__ csr_src) {
    int e = blockIdx.x * 256 + threadIdx.x;
    if (e >= N_EDGES) return;
    int p = atomicAdd(&pos[dst[e]], 1);
    csr_src[p] = src[e];
}

// ---------------- gather aggregation: agg[n] = sum_{e: dst=n} m[src[e]] ----------------
__global__ __launch_bounds__(256) void gather_agg(const float* __restrict__ m,
                                                  const int* __restrict__ row_ptr,
                                                  const int* __restrict__ csr_src,
                                                  float* __restrict__ agg) {
    int t = threadIdx.x;
    int node = blockIdx.x * 8 + (t >> 5);
    int c4 = (t & 31) * 4;
    if (node >= N_NODES) return;
    int b = row_ptr[node];
    int e2 = row_ptr[node + 1];
    float4 acc = make_float4(0.f, 0.f, 0.f, 0.f);
    for (int e = b; e < e2; ++e) {
        int s = csr_src[e];
        float4 v = *(const float4*)(m + (size_t)s * D + c4);
        acc.x += v.x; acc.y += v.y; acc.z += v.z; acc.w += v.w;
    }
    *(float4*)(agg + (size_t)node * D + c4) = acc;
}

// ---------------- GEMM: C[i,j] = sum_k A[i,k] * W[j,k] (+bias) ----------------
// MODE 0: C[i*J + j] = acc + bias[j]           (bias may be null)
// MODE 1: (GRU gh pass, J==384)
//         j < 256 : C[i*384 + j] += acc + bias[j]     (sum into gi r/z parts)
//         j >= 256: C2[i*128 + (j-256)] = acc + bias[j]  (h_n)
template <int MODE>
__global__ __launch_bounds__(256) void gemm_nt(const float* __restrict__ A,
                                               const float* __restrict__ W,
                                               const float* __restrict__ bias,
                                               float* __restrict__ C,
                                               float* __restrict__ C2,
                                               int M, int J) {
    __shared__ float As[64][132];
    __shared__ float Bs[64][132];
    int i0 = blockIdx.x * 64;
    int j0 = blockIdx.y * 64;
    int tid = threadIdx.x;

    {
        int r = tid >> 5;
        int c4 = (tid & 31) * 4;
        #pragma unroll
        for (int it = 0; it < 8; ++it, r += 8) {
            int gi_ = i0 + r;
            float4 v = make_float4(0.f, 0.f, 0.f, 0.f);
            if (gi_ < M) v = *(const float4*)(A + (size_t)gi_ * D + c4);
            *(float4*)&As[r][c4] = v;
            float4 w = *(const float4*)(W + (size_t)(j0 + r) * D + c4);
            *(float4*)&Bs[r][c4] = w;
        }
    }
    __syncthreads();

    int tr = (tid >> 4) * 4;
    int tc = (tid & 15) * 4;
    float acc[4][4] = {};

    for (int k = 0; k < D; k += 4) {
        float4 a[4], b[4];
        #pragma unroll
        for (int p = 0; p < 4; ++p) a[p] = *(float4*)&As[tr + p][k];
        #pragma unroll
        for (int q = 0; q < 4; ++q) b[q] = *(float4*)&Bs[tc + q][k];
        #pragma unroll
        for (int p = 0; p < 4; ++p)
            #pragma unroll
            for (int q = 0; q < 4; ++q)
                acc[p][q] += a[p].x * b[q].x + a[p].y * b[q].y +
                             a[p].z * b[q].z + a[p].w * b[q].w;
    }

    #pragma unroll
    for (int p = 0; p < 4; ++p) {
        int i = i0 + tr + p;
        if (i >= M) continue;
        #pragma unroll
        for (int q = 0; q < 4; ++q) {
            int j = j0 + tc + q;
            float v = acc[p][q] + (bias ? bias[j] : 0.f);
            if (MODE == 0) {
                C[(size_t)i * J + j] = v;
            } else {
                if (j < 256) C[(size_t)i * 384 + j] += v;
                else         C2[(size_t)i * 128 + (j - 256)] = v;
            }
        }
    }
}

// ---------------- GRU gates + relu, h updated in place ----------------
__global__ __launch_bounds__(256) void gru_gates(const float* __restrict__ gi,
                                                 const float* __restrict__ hn,
                                                 float* __restrict__ h) {
    int idx = blockIdx.x * 256 + threadIdx.x;   // N*D
    if (idx >= N_NODES * D) return;
    int i = idx >> 7;
    int c = idx & 127;
    size_t base = (size_t)i * 384;
    float g_r = gi[base + c];
    float g_z = gi[base + 128 + c];
    float i_n = gi[base + 256 + c];
    float h_n = hn[(size_t)i * 128 + c];
    float r = 1.f / (1.f + expf(-g_r));
    float z = 1.f / (1.f + expf(-g_z));
    float n = tanhf(i_n + r * h_n);
    float h_old = h[idx];
    float h_new = (1.f - z) * n + z * h_old;
    h[idx] = h_new > 0.f ? h_new : 0.f;
}

// ---------------- mean pool over sorted batch: one block per graph ----------------
__global__ __launch_bounds__(128) void pool_sorted(const float* __restrict__ h,
                                                   const int* __restrict__ batch,
                                                   float* __restrict__ hg) {
    int g = blockIdx.x;
    int c = threadIdx.x;
    // lower_bound for g and g+1
    int lo = 0, hi = N_NODES;
    while (lo < hi) { int mid = (lo + hi) >> 1; if (batch[mid] < g) lo = mid + 1; else hi = mid; }
    int start = lo;
    lo = start; hi = N_NODES;
    while (lo < hi) { int mid = (lo + hi) >> 1; if (batch[mid] < g + 1) lo = mid + 1; else hi = mid; }
    int end = lo;
    float s = 0.f;
    for (int i = start; i < end; ++i) s += h[(size_t)i * D + c];
    float cnt = (float)(end - start);
    hg[(size_t)g * D + c] = s / fmaxf(cnt, 1.f);
}

// ---------------- fc1 + elu ----------------
__global__ __launch_bounds__(128) void fc1_elu(const float* __restrict__ hg,
                                               const float* __restrict__ w,
                                               const float* __restrict__ b,
                                               float* __restrict__ z) {
    __shared__ float row[128];
    int g = blockIdx.x;
    int j = threadIdx.x;
    row[j] = hg[(size_t)g * 128 + j];
    __syncthreads();
    float acc = b[j];
    const float* wr = w + (size_t)j * 128;
    #pragma unroll 4
    for (int k = 0; k < 128; ++k) acc += row[k] * wr[k];
    z[(size_t)g * 128 + j] = acc > 0.f ? acc : (expf(acc) - 1.f);
}

// ---------------- fc2 ----------------
__global__ __launch_bounds__(64) void fc2_k(const float* __restrict__ z,
                                            const float* __restrict__ w,
                                            const float* __restrict__ b,
                                            float* __restrict__ logits) {
    __shared__ float row[128];
    int g = blockIdx.x;
    int t = threadIdx.x;
    row[t] = z[(size_t)g * 128 + t];
    row[t + 64] = z[(size_t)g * 128 + 64 + t];
    __syncthreads();
    if (t < N_CLASSES) {
        float acc = b[t];
        const float* wr = w + (size_t)t * 128;
        #pragma unroll 4
        for (int k = 0; k < 128; ++k) acc += row[k] * wr[k];
        logits[(size_t)g * N_CLASSES + t] = acc;
    }
}

// ---------------- log_softmax over axis 0 (graphs), per class ----------------
__global__ __launch_bounds__(512) void logsoftmax_axis0(const float* __restrict__ logits,
                                                        float* __restrict__ out) {
    __shared__ float red[512];
    int c = blockIdx.x;
    int g = threadIdx.x;
    float x = logits[(size_t)g * N_CLASSES + c];
    red[g] = x;
    __syncthreads();
    for (int s = 256; s > 0; s >>= 1) {
        if (g < s) red[g] = fmaxf(red[g], red[g + s]);
        __syncthreads();
    }
    float mx = red[0];
    __syncthreads();
    red[g] = expf(x - mx);
    __syncthreads();
    for (int s = 256; s > 0; s >>= 1) {
        if (g < s) red[g] += red[g + s];
        __syncthreads();
    }
    float lse = mx + logf(red[0]);
    out[(size_t)g * N_CLASSES + c] = x - lse;
}

// ---------------- launch ----------------
extern "C" void kernel_launch(void* const* d_in, const int* in_sizes, int n_in,
                              void* d_out, int out_size, void* d_ws, size_t ws_size,
                              hipStream_t stream) {
    const float* h_in   = (const float*)d_in[0];
    const int*   eidx   = (const int*)d_in[1];
    const int*   batch  = (const int*)d_in[3];
    const float* Ws     = (const float*)d_in[4];
    const float* W_ih   = (const float*)d_in[5];
    const float* W_hh   = (const float*)d_in[6];
    const float* b_ih   = (const float*)d_in[7];
    const float* b_hh   = (const float*)d_in[8];
    const float* fc1_w  = (const float*)d_in[9];
    const float* fc1_b  = (const float*)d_in[10];
    const float* fc2_w  = (const float*)d_in[11];
    const float* fc2_b  = (const float*)d_in[12];
    float* out = (float*)d_out;

    char* ws = (char*)d_ws;
    size_t off = 0;
    auto alloc = [&](size_t bytes) {
        void* p = ws + off;
        off += (bytes + 255) & ~(size_t)255;
        return p;
    };
    float* h    = (float*)alloc((size_t)N_NODES * D * 4);
    float* m    = (float*)alloc((size_t)N_NODES * D * 4);   // also reused as h_n
    float* agg  = (float*)alloc((size_t)N_NODES * D * 4);
    float* gi   = (float*)alloc((size_t)N_NODES * 384 * 4);
    float* WsT  = (float*)alloc((size_t)N_LAYERS * D * D * 4);
    float* hg   = (float*)alloc((size_t)N_GRAPHS * D * 4);
    float* zb   = (float*)alloc((size_t)N_GRAPHS * D * 4);
    float* lgts = (float*)alloc((size_t)N_GRAPHS * N_CLASSES * 4);
    int* deg     = (int*)alloc((size_t)N_NODES * 4);
    int* row_ptr = (int*)alloc((size_t)(N_NODES + 1) * 4);
    int* pos     = (int*)alloc((size_t)N_NODES * 4);
    int* csr_src = (int*)alloc((size_t)N_EDGES * 4);

    const int* src = eidx;
    const int* dst = eidx + N_EDGES;

    hipMemcpyAsync(h, h_in, (size_t)N_NODES * D * 4, hipMemcpyDeviceToDevice, stream);
    transpose_ws<<<256, 256, 0, stream>>>(Ws, WsT);

    // ---- CSR build (once; edges are static) ----
    fill_zero4<<<(N_NODES / 4 + 255) / 256, 256, 0, stream>>>((float4*)deg, N_NODES / 4);
    hist_dst<<<(N_EDGES + 255) / 256, 256, 0, stream>>>(dst, deg);
    scan_deg<<<1, 1024, 0, stream>>>(deg, row_ptr, pos);
    fill_csr<<<(N_EDGES + 255) / 256, 256, 0, stream>>>(src, dst, pos, csr_src);

    const int mtiles = (N_NODES + 63) / 64;   // 782
    for (int l = 0; l < N_LAYERS; ++l) {
        gemm_nt<0><<<dim3(mtiles, 2), 256, 0, stream>>>(h, WsT + (size_t)l * D * D,
                                                        nullptr, m, nullptr, N_NODES, 128);
        gather_agg<<<(N_NODES + 7) / 8, 256, 0, stream>>>(m, row_ptr, csr_src, agg);
        gemm_nt<0><<<dim3(mtiles, 6), 256, 0, stream>>>(agg, W_ih + (size_t)l * 384 * D,
                                                        b_ih + (size_t)l * 384, gi, nullptr,
                                                        N_NODES, 384);
        gemm_nt<1><<<dim3(mtiles, 6), 256, 0, stream>>>(h, W_hh + (size_t)l * 384 * D,
                                                        b_hh + (size_t)l * 384, gi, m,
                                                        N_NODES, 384);
        gru_gates<<<(N_NODES * D + 255) / 256, 256, 0, stream>>>(gi, m, h);
    }

    pool_sorted<<<N_GRAPHS, 128, 0, stream>>>(h, batch, hg);
    fc1_elu<<<N_GRAPHS, 128, 0, stream>>>(hg, fc1_w, fc1_b, zb);
    fc2_k<<<N_GRAPHS, 64, 0, stream>>>(zb, fc2_w, fc2_b, lgts);
    logsoftmax_axis0<<<N_CLASSES, 512, 0, stream>>>(lgts, out);
}

// Round 3
// 990.624 us; speedup vs baseline: 5.8203x; 1.9612x over previous
//
#include <hip/hip_runtime.h>
#include <math.h>

#define N_NODES 50000
#define N_EDGES 600000
#define D 128
#define N_GRAPHS 512
#define N_CLASSES 10
#define N_LAYERS 4

typedef __attribute__((ext_vector_type(8))) short bf16x8;
typedef __attribute__((ext_vector_type(4))) float f32x4;

__device__ inline unsigned short f2bf(float f) {
    union { float f; unsigned int u; } v; v.f = f;
    unsigned int r = (v.u + 0x7fffu + ((v.u >> 16) & 1u)) >> 16;
    return (unsigned short)r;
}
__device__ inline float bf2f(unsigned short u) {
    union { unsigned int u; float f; } v; v.u = ((unsigned int)u) << 16;
    return v.f;
}

// ---------------- zero fill ----------------
__global__ __launch_bounds__(256) void fill_zero4(float4* p, int n4) {
    int i = blockIdx.x * 256 + threadIdx.x;
    if (i < n4) p[i] = make_float4(0.f, 0.f, 0.f, 0.f);
}

// ---------------- weight conversion (once): fp32 -> bf16 ----------------
// WsT_bf[l][j][k] = Ws[l][k][j]; Wih/Whh straight copy (already [n][k])
__global__ __launch_bounds__(256) void convert_weights(const float* __restrict__ Ws,
                                                       const float* __restrict__ Wih,
                                                       const float* __restrict__ Whh,
                                                       unsigned short* __restrict__ WsT_bf,
                                                       unsigned short* __restrict__ Wih_bf,
                                                       unsigned short* __restrict__ Whh_bf) {
    int idx = blockIdx.x * 256 + threadIdx.x;
    if (idx < N_LAYERS * D * D) {
        int l = idx >> 14, rem = idx & 16383, j = rem >> 7, k = rem & 127;
        WsT_bf[idx] = f2bf(Ws[(l << 14) + (k << 7) + j]);
    }
    if (idx < N_LAYERS * 3 * D * D) {
        Wih_bf[idx] = f2bf(Wih[idx]);
        Whh_bf[idx] = f2bf(Whh[idx]);
    }
}

// ---------------- h init: copy fp32 + make bf16 mirror ----------------
__global__ __launch_bounds__(256) void convert_h(const float* __restrict__ h_in,
                                                 float* __restrict__ h,
                                                 unsigned short* __restrict__ hb) {
    int idx = blockIdx.x * 256 + threadIdx.x;
    if (idx >= N_NODES * D) return;
    float v = h_in[idx];
    h[idx] = v;
    hb[idx] = f2bf(v);
}

// ---------------- CSR build ----------------
__global__ __launch_bounds__(256) void hist_dst(const int* __restrict__ dst,
                                                int* __restrict__ deg) {
    int e = blockIdx.x * 256 + threadIdx.x;
    if (e < N_EDGES) atomicAdd(&deg[dst[e]], 1);
}

__global__ __launch_bounds__(1024) void scan_deg(const int* __restrict__ deg,
                                                 int* __restrict__ row_ptr,
                                                 int* __restrict__ pos) {
    __shared__ int part[1024];
    const int CHUNK = (N_NODES + 1023) / 1024;
    int t = threadIdx.x;
    int start = t * CHUNK;
    int end = min(start + CHUNK, N_NODES);
    int s = 0;
    for (int i = start; i < end; ++i) s += deg[i];
    part[t] = s;
    __syncthreads();
    for (int off = 1; off < 1024; off <<= 1) {
        int v = (t >= off) ? part[t - off] : 0;
        __syncthreads();
        part[t] += v;
        __syncthreads();
    }
    int run = (t == 0) ? 0 : part[t - 1];
    for (int i = start; i < end; ++i) {
        row_ptr[i] = run;
        pos[i] = run;
        run += deg[i];
    }
    if (t == 1023) row_ptr[N_NODES] = part[1023];
}

__global__ __launch_bounds__(256) void fill_csr(const int* __restrict__ src,
                                                const int* __restrict__ dst,
                                                int* __restrict__ pos,
                                                int* __restrict__ csr_src) {
    int e = blockIdx.x * 256 + threadIdx.x;
    if (e >= N_EDGES) return;
    int p = atomicAdd(&pos[dst[e]], 1);
    csr_src[p] = src[e];
}

// ---------------- gather aggregation (bf16 in, bf16 out, fp32 accum) ----------------
__global__ __launch_bounds__(256) void gather_agg(const unsigned short* __restrict__ mb,
                                                  const int* __restrict__ row_ptr,
                                                  const int* __restrict__ csr_src,
                                                  unsigned short* __restrict__ aggb) {
    int t = threadIdx.x;
    int node = blockIdx.x * 16 + (t >> 4);
    int c8 = (t & 15) * 8;
    if (node >= N_NODES) return;
    int b = row_ptr[node];
    int e2 = row_ptr[node + 1];
    float acc[8] = {};
    for (int e = b; e < e2; ++e) {
        int s = csr_src[e];
        bf16x8 v = *(const bf16x8*)(mb + (size_t)s * D + c8);
        #pragma unroll
        for (int j = 0; j < 8; ++j) acc[j] += bf2f((unsigned short)v[j]);
    }
    bf16x8 ov;
    #pragma unroll
    for (int j = 0; j < 8; ++j) ov[j] = (short)f2bf(acc[j]);
    *(bf16x8*)(aggb + (size_t)node * D + c8) = ov;
}

// ---------------- bf16 MFMA GEMM: acc[i,j] = sum_k A[i,k] * W[j,k] ----------------
// A: [M][128] bf16.  W: [N][128] bf16.  128x128 output tile per block, 4 waves.
// MODE 0: C[i*N + j]          = acc + bias[j]   (fp32 out; gi)
// MODE 1: j<256: C[i*384+j]  += acc + bias[j];  j>=256: C2[i*128+(j-256)] = acc + bias[j]
// MODE 2: Cb[i*128 + j]       = bf16(acc)       (m = h@Ws)
template <int MODE>
__global__ __launch_bounds__(256) void gemm_mfma(const unsigned short* __restrict__ A,
                                                 const unsigned short* __restrict__ W,
                                                 const float* __restrict__ bias,
                                                 float* __restrict__ C,
                                                 float* __restrict__ C2,
                                                 unsigned short* __restrict__ Cb,
                                                 int M, int N) {
    // pitch 72 ushort = 144 B: 16B-aligned rows, uniform bank spread for b128 reads
    __shared__ unsigned short As[128 * 72];
    __shared__ unsigned short Bs[128 * 72];

    const int tid = threadIdx.x;
    const int i0 = blockIdx.x * 128;
    const int j0 = blockIdx.y * 128;

    const int wave = tid >> 6;
    const int lane = tid & 63;
    const int m16 = lane & 15;
    const int quad = lane >> 4;
    const int mr = (wave & 1) * 64;   // wave's row half
    const int nc = (wave >> 1) * 64;  // wave's col half

    f32x4 acc[4][4];
    #pragma unroll
    for (int a = 0; a < 4; ++a)
        #pragma unroll
        for (int b = 0; b < 4; ++b)
            acc[a][b] = (f32x4){0.f, 0.f, 0.f, 0.f};

    const int r0 = tid >> 3;          // 0..31
    const int kk = (tid & 7) * 8;     // 0..56

    for (int kc = 0; kc < 128; kc += 64) {
        if (kc) __syncthreads();
        #pragma unroll
        for (int it = 0; it < 4; ++it) {
            int r = r0 + it * 32;
            int gi_ = i0 + r;
            bf16x8 av = {0, 0, 0, 0, 0, 0, 0, 0};
            if (gi_ < M) av = *(const bf16x8*)(A + (size_t)gi_ * 128 + kc + kk);
            *(bf16x8*)&As[r * 72 + kk] = av;
            *(bf16x8*)&Bs[r * 72 + kk] = *(const bf16x8*)(W + (size_t)(j0 + r) * 128 + kc + kk);
        }
        __syncthreads();

        #pragma unroll
        for (int ks = 0; ks < 64; ks += 32) {
            bf16x8 af[4], bf_[4];
            #pragma unroll
            for (int rt = 0; rt < 4; ++rt)
                af[rt] = *(const bf16x8*)&As[(mr + rt * 16 + m16) * 72 + ks + quad * 8];
            #pragma unroll
            for (int ct = 0; ct < 4; ++ct)
                bf_[ct] = *(const bf16x8*)&Bs[(nc + ct * 16 + m16) * 72 + ks + quad * 8];
            #pragma unroll
            for (int rt = 0; rt < 4; ++rt)
                #pragma unroll
                for (int ct = 0; ct < 4; ++ct)
                    acc[rt][ct] = __builtin_amdgcn_mfma_f32_16x16x32_bf16(
                        af[rt], bf_[ct], acc[rt][ct], 0, 0, 0);
        }
    }

    // epilogue: C/D layout col=lane&15, row=quad*4+reg
    #pragma unroll
    for (int rt = 0; rt < 4; ++rt) {
        #pragma unroll
        for (int r4 = 0; r4 < 4; ++r4) {
            int i = i0 + mr + rt * 16 + quad * 4 + r4;
            if (i >= M) continue;
            #pragma unroll
            for (int ct = 0; ct < 4; ++ct) {
                int j = j0 + nc + ct * 16 + m16;
                float v = acc[rt][ct][r4];
                if (MODE != 2 && bias) v += bias[j];
                if (MODE == 0) {
                    C[(size_t)i * N + j] = v;
                } else if (MODE == 1) {
                    if (j < 256) C[(size_t)i * 384 + j] += v;
                    else         C2[(size_t)i * 128 + (j - 256)] = v;
                } else {
                    Cb[(size_t)i * 128 + j] = f2bf(v);
                }
            }
        }
    }
}

// ---------------- GRU gates + relu; h fp32 in/out, bf16 mirror out ----------------
__global__ __launch_bounds__(256) void gru_gates(const float* __restrict__ gi,
                                                 const float* __restrict__ hn,
                                                 float* __restrict__ h,
                                                 unsigned short* __restrict__ hb) {
    int idx = blockIdx.x * 256 + threadIdx.x;   // N*32
    if (idx >= N_NODES * 32) return;
    int i = idx >> 5;
    int c = (idx & 31) * 4;
    size_t base = (size_t)i * 384;
    float4 gr = *(const float4*)(gi + base + c);
    float4 gz = *(const float4*)(gi + base + 128 + c);
    float4 gn = *(const float4*)(gi + base + 256 + c);
    float4 hnv = *(const float4*)(hn + (size_t)i * 128 + c);
    float4 ho = *(const float4*)(h + (size_t)i * 128 + c);
    float4 hv;
    {
        float r = 1.f / (1.f + expf(-gr.x));
        float z = 1.f / (1.f + expf(-gz.x));
        float n = tanhf(gn.x + r * hnv.x);
        float o = (1.f - z) * n + z * ho.x;
        hv.x = o > 0.f ? o : 0.f;
    }
    {
        float r = 1.f / (1.f + expf(-gr.y));
        float z = 1.f / (1.f + expf(-gz.y));
        float n = tanhf(gn.y + r * hnv.y);
        float o = (1.f - z) * n + z * ho.y;
        hv.y = o > 0.f ? o : 0.f;
    }
    {
        float r = 1.f / (1.f + expf(-gr.z));
        float z = 1.f / (1.f + expf(-gz.z));
        float n = tanhf(gn.z + r * hnv.z);
        float o = (1.f - z) * n + z * ho.z;
        hv.z = o > 0.f ? o : 0.f;
    }
    {
        float r = 1.f / (1.f + expf(-gr.w));
        float z = 1.f / (1.f + expf(-gz.w));
        float n = tanhf(gn.w + r * hnv.w);
        float o = (1.f - z) * n + z * ho.w;
        hv.w = o > 0.f ? o : 0.f;
    }
    *(float4*)(h + (size_t)i * 128 + c) = hv;
    ushort4 hb4;
    hb4.x = f2bf(hv.x); hb4.y = f2bf(hv.y); hb4.z = f2bf(hv.z); hb4.w = f2bf(hv.w);
    *(ushort4*)(hb + (size_t)i * 128 + c) = hb4;
}

// ---------------- mean pool over sorted batch ----------------
__global__ __launch_bounds__(128) void pool_sorted(const float* __restrict__ h,
                                                   const int* __restrict__ batch,
                                                   float* __restrict__ hg) {
    int g = blockIdx.x;
    int c = threadIdx.x;
    int lo = 0, hi = N_NODES;
    while (lo < hi) { int mid = (lo + hi) >> 1; if (batch[mid] < g) lo = mid + 1; else hi = mid; }
    int start = lo;
    lo = start; hi = N_NODES;
    while (lo < hi) { int mid = (lo + hi) >> 1; if (batch[mid] < g + 1) lo = mid + 1; else hi = mid; }
    int end = lo;
    float s = 0.f;
    for (int i = start; i < end; ++i) s += h[(size_t)i * D + c];
    float cnt = (float)(end - start);
    hg[(size_t)g * D + c] = s / fmaxf(cnt, 1.f);
}

// ---------------- fc1 + elu ----------------
__global__ __launch_bounds__(128) void fc1_elu(const float* __restrict__ hg,
                                               const float* __restrict__ w,
                                               const float* __restrict__ b,
                                               float* __restrict__ z) {
    __shared__ float row[128];
    int g = blockIdx.x;
    int j = threadIdx.x;
    row[j] = hg[(size_t)g * 128 + j];
    __syncthreads();
    float acc = b[j];
    const float* wr = w + (size_t)j * 128;
    #pragma unroll 4
    for (int k = 0; k < 128; ++k) acc += row[k] * wr[k];
    z[(size_t)g * 128 + j] = acc > 0.f ? acc : (expf(acc) - 1.f);
}

// ---------------- fc2 ----------------
__global__ __launch_bounds__(64) void fc2_k(const float* __restrict__ z,
                                            const float* __restrict__ w,
                                            const float* __restrict__ b,
                                            float* __restrict__ logits) {
    __shared__ float row[128];
    int g = blockIdx.x;
    int t = threadIdx.x;
    row[t] = z[(size_t)g * 128 + t];
    row[t + 64] = z[(size_t)g * 128 + 64 + t];
    __syncthreads();
    if (t < N_CLASSES) {
        float acc = b[t];
        const float* wr = w + (size_t)t * 128;
        #pragma unroll 4
        for (int k = 0; k < 128; ++k) acc += row[k] * wr[k];
        logits[(size_t)g * N_CLASSES + t] = acc;
    }
}

// ---------------- log_softmax over axis 0 ----------------
__global__ __launch_bounds__(512) void logsoftmax_axis0(const float* __restrict__ logits,
                                                        float* __restrict__ out) {
    __shared__ float red[512];
    int c = blockIdx.x;
    int g = threadIdx.x;
    float x = logits[(size_t)g * N_CLASSES + c];
    red[g] = x;
    __syncthreads();
    for (int s = 256; s > 0; s >>= 1) {
        if (g < s) red[g] = fmaxf(red[g], red[g + s]);
        __syncthreads();
    }
    float mx = red[0];
    __syncthreads();
    red[g] = expf(x - mx);
    __syncthreads();
    for (int s = 256; s > 0; s >>= 1) {
        if (g < s) red[g] += red[g + s];
        __syncthreads();
    }
    float lse = mx + logf(red[0]);
    out[(size_t)g * N_CLASSES + c] = x - lse;
}

// ---------------- launch ----------------
extern "C" void kernel_launch(void* const* d_in, const int* in_sizes, int n_in,
                              void* d_out, int out_size, void* d_ws, size_t ws_size,
                              hipStream_t stream) {
    const float* h_in   = (const float*)d_in[0];
    const int*   eidx   = (const int*)d_in[1];
    const int*   batch  = (const int*)d_in[3];
    const float* Ws     = (const float*)d_in[4];
    const float* W_ih   = (const float*)d_in[5];
    const float* W_hh   = (const float*)d_in[6];
    const float* b_ih   = (const float*)d_in[7];
    const float* b_hh   = (const float*)d_in[8];
    const float* fc1_w  = (const float*)d_in[9];
    const float* fc1_b  = (const float*)d_in[10];
    const float* fc2_w  = (const float*)d_in[11];
    const float* fc2_b  = (const float*)d_in[12];
    float* out = (float*)d_out;

    char* ws = (char*)d_ws;
    size_t off = 0;
    auto alloc = [&](size_t bytes) {
        void* p = ws + off;
        off += (bytes + 255) & ~(size_t)255;
        return p;
    };
    float* h            = (float*)alloc((size_t)N_NODES * D * 4);
    float* gi           = (float*)alloc((size_t)N_NODES * 384 * 4);
    float* hn           = (float*)alloc((size_t)N_NODES * D * 4);
    unsigned short* hb  = (unsigned short*)alloc((size_t)N_NODES * D * 2);
    unsigned short* mb  = (unsigned short*)alloc((size_t)N_NODES * D * 2);
    unsigned short* aggb= (unsigned short*)alloc((size_t)N_NODES * D * 2);
    unsigned short* WsT_bf = (unsigned short*)alloc((size_t)N_LAYERS * D * D * 2);
    unsigned short* Wih_bf = (unsigned short*)alloc((size_t)N_LAYERS * 3 * D * D * 2);
    unsigned short* Whh_bf = (unsigned short*)alloc((size_t)N_LAYERS * 3 * D * D * 2);
    float* hg   = (float*)alloc((size_t)N_GRAPHS * D * 4);
    float* zb   = (float*)alloc((size_t)N_GRAPHS * D * 4);
    float* lgts = (float*)alloc((size_t)N_GRAPHS * N_CLASSES * 4);
    int* deg     = (int*)alloc((size_t)N_NODES * 4);
    int* row_ptr = (int*)alloc((size_t)(N_NODES + 1) * 4);
    int* pos     = (int*)alloc((size_t)N_NODES * 4);
    int* csr_src = (int*)alloc((size_t)N_EDGES * 4);

    const int* src = eidx;
    const int* dst = eidx + N_EDGES;

    convert_h<<<(N_NODES * D + 255) / 256, 256, 0, stream>>>(h_in, h, hb);
    convert_weights<<<(N_LAYERS * 3 * D * D + 255) / 256, 256, 0, stream>>>(
        Ws, W_ih, W_hh, WsT_bf, Wih_bf, Whh_bf);

    // CSR build (edges static)
    fill_zero4<<<(N_NODES / 4 + 255) / 256, 256, 0, stream>>>((float4*)deg, N_NODES / 4);
    hist_dst<<<(N_EDGES + 255) / 256, 256, 0, stream>>>(dst, deg);
    scan_deg<<<1, 1024, 0, stream>>>(deg, row_ptr, pos);
    fill_csr<<<(N_EDGES + 255) / 256, 256, 0, stream>>>(src, dst, pos, csr_src);

    const int mtiles = (N_NODES + 127) / 128;   // 391
    for (int l = 0; l < N_LAYERS; ++l) {
        // m = h @ Ws[l]  (bf16 out)
        gemm_mfma<2><<<dim3(mtiles, 1), 256, 0, stream>>>(
            hb, WsT_bf + (size_t)l * D * D, nullptr, nullptr, nullptr, mb, N_NODES, 128);
        // agg = gather(m)
        gather_agg<<<(N_NODES + 15) / 16, 256, 0, stream>>>(mb, row_ptr, csr_src, aggb);
        // gi = agg @ W_ih^T + b_ih
        gemm_mfma<0><<<dim3(mtiles, 3), 256, 0, stream>>>(
            aggb, Wih_bf + (size_t)l * 3 * D * D, b_ih + (size_t)l * 384, gi, nullptr, nullptr,
            N_NODES, 384);
        // gh: gi[:, :256] += h @ W_hh^T + b_hh ; hn = cols 256:384
        gemm_mfma<1><<<dim3(mtiles, 3), 256, 0, stream>>>(
            hb, Whh_bf + (size_t)l * 3 * D * D, b_hh + (size_t)l * 384, gi, hn, nullptr,
            N_NODES, 384);
        gru_gates<<<(N_NODES * 32 + 255) / 256, 256, 0, stream>>>(gi, hn, h, hb);
    }

    pool_sorted<<<N_GRAPHS, 128, 0, stream>>>(h, batch, hg);
    fc1_elu<<<N_GRAPHS, 128, 0, stream>>>(hg, fc1_w, fc1_b, zb);
    fc2_k<<<N_GRAPHS, 64, 0, stream>>>(zb, fc2_w, fc2_b, lgts);
    logsoftmax_axis0<<<N_CLASSES, 512, 0, stream>>>(lgts, out);
}

// Round 4
// 880.340 us; speedup vs baseline: 6.5495x; 1.1253x over previous
//
#include <hip/hip_runtime.h>
#include <math.h>

#define N_NODES 50000
#define N_EDGES 600000
#define D 128
#define N_GRAPHS 512
#define N_CLASSES 10
#define N_LAYERS 4
#define NBLK_SCAN 196   // ceil(50000/256)

typedef __attribute__((ext_vector_type(8))) short bf16x8;
typedef __attribute__((ext_vector_type(4))) float f32x4;

__device__ inline unsigned short f2bf(float f) {
    union { float f; unsigned int u; } v; v.f = f;
    unsigned int r = (v.u + 0x7fffu + ((v.u >> 16) & 1u)) >> 16;
    return (unsigned short)r;
}
__device__ inline float bf2f(unsigned short u) {
    union { unsigned int u; float f; } v; v.u = ((unsigned int)u) << 16;
    return v.f;
}

// ---------------- zero fill ----------------
__global__ __launch_bounds__(256) void fill_zero4(float4* p, int n4) {
    int i = blockIdx.x * 256 + threadIdx.x;
    if (i < n4) p[i] = make_float4(0.f, 0.f, 0.f, 0.f);
}

// ---------------- weight conversion (once): fp32 -> bf16 ----------------
__global__ __launch_bounds__(256) void convert_weights(const float* __restrict__ Ws,
                                                       const float* __restrict__ Wih,
                                                       const float* __restrict__ Whh,
                                                       unsigned short* __restrict__ WsT_bf,
                                                       unsigned short* __restrict__ Wih_bf,
                                                       unsigned short* __restrict__ Whh_bf) {
    int idx = blockIdx.x * 256 + threadIdx.x;
    if (idx < N_LAYERS * D * D) {
        int l = idx >> 14, rem = idx & 16383, j = rem >> 7, k = rem & 127;
        WsT_bf[idx] = f2bf(Ws[(l << 14) + (k << 7) + j]);
    }
    if (idx < N_LAYERS * 3 * D * D) {
        Wih_bf[idx] = f2bf(Wih[idx]);
        Whh_bf[idx] = f2bf(Whh[idx]);
    }
}

// ---------------- h init ----------------
__global__ __launch_bounds__(256) void convert_h(const float* __restrict__ h_in,
                                                 float* __restrict__ h,
                                                 unsigned short* __restrict__ hb) {
    int idx = blockIdx.x * 256 + threadIdx.x;
    if (idx >= N_NODES * D) return;
    float v = h_in[idx];
    h[idx] = v;
    hb[idx] = f2bf(v);
}

// ---------------- CSR build ----------------
__global__ __launch_bounds__(256) void hist_dst(const int* __restrict__ dst,
                                                int* __restrict__ deg) {
    int e = blockIdx.x * 256 + threadIdx.x;
    if (e < N_EDGES) atomicAdd(&deg[dst[e]], 1);
}

__global__ __launch_bounds__(256) void block_sum(const int* __restrict__ deg,
                                                 int* __restrict__ bsum) {
    __shared__ int s[256];
    int t = threadIdx.x;
    int i = blockIdx.x * 256 + t;
    s[t] = (i < N_NODES) ? deg[i] : 0;
    __syncthreads();
    for (int o = 128; o > 0; o >>= 1) {
        if (t < o) s[t] += s[t + o];
        __syncthreads();
    }
    if (t == 0) bsum[blockIdx.x] = s[0];
}

__global__ __launch_bounds__(256) void scan_partials(const int* __restrict__ bsum,
                                                     int* __restrict__ boff,
                                                     int* __restrict__ row_ptr) {
    __shared__ int s[256];
    int t = threadIdx.x;
    int v = (t < NBLK_SCAN) ? bsum[t] : 0;
    s[t] = v;
    __syncthreads();
    for (int o = 1; o < 256; o <<= 1) {
        int x = (t >= o) ? s[t - o] : 0;
        __syncthreads();
        s[t] += x;
        __syncthreads();
    }
    if (t < NBLK_SCAN) boff[t] = s[t] - v;   // exclusive
    if (t == 255) row_ptr[N_NODES] = s[255];
}

__global__ __launch_bounds__(256) void scan_final(const int* __restrict__ deg,
                                                  const int* __restrict__ boff,
                                                  int* __restrict__ row_ptr,
                                                  int* __restrict__ pos) {
    __shared__ int s[256];
    int t = threadIdx.x;
    int i = blockIdx.x * 256 + t;
    int v = (i < N_NODES) ? deg[i] : 0;
    s[t] = v;
    __syncthreads();
    for (int o = 1; o < 256; o <<= 1) {
        int x = (t >= o) ? s[t - o] : 0;
        __syncthreads();
        s[t] += x;
        __syncthreads();
    }
    int excl = s[t] - v + boff[blockIdx.x];
    if (i < N_NODES) {
        row_ptr[i] = excl;
        pos[i] = excl;
    }
}

__global__ __launch_bounds__(256) void fill_csr(const int* __restrict__ src,
                                                const int* __restrict__ dst,
                                                int* __restrict__ pos,
                                                int* __restrict__ csr_src) {
    int e = blockIdx.x * 256 + threadIdx.x;
    if (e >= N_EDGES) return;
    int p = atomicAdd(&pos[dst[e]], 1);
    csr_src[p] = src[e];
}

// ---------------- gather aggregation (bf16 in/out, fp32 accum) ----------------
__global__ __launch_bounds__(256) void gather_agg(const unsigned short* __restrict__ mb,
                                                  const int* __restrict__ row_ptr,
                                                  const int* __restrict__ csr_src,
                                                  unsigned short* __restrict__ aggb) {
    int t = threadIdx.x;
    int node = blockIdx.x * 16 + (t >> 4);
    int c8 = (t & 15) * 8;
    if (node >= N_NODES) return;
    int b = row_ptr[node];
    int e2 = row_ptr[node + 1];
    float acc[8] = {};
    for (int e = b; e < e2; ++e) {
        int s = csr_src[e];
        bf16x8 v = *(const bf16x8*)(mb + (size_t)s * D + c8);
        #pragma unroll
        for (int j = 0; j < 8; ++j) acc[j] += bf2f((unsigned short)v[j]);
    }
    bf16x8 ov;
    #pragma unroll
    for (int j = 0; j < 8; ++j) ov[j] = (short)f2bf(acc[j]);
    *(bf16x8*)(aggb + (size_t)node * D + c8) = ov;
}

// ---------------- m = h @ Ws (bf16 out), 128x128 tile MFMA ----------------
__global__ __launch_bounds__(256) void gemm_m(const unsigned short* __restrict__ A,
                                              const unsigned short* __restrict__ W,
                                              unsigned short* __restrict__ Cb,
                                              int M) {
    __shared__ unsigned short As[128 * 72];
    __shared__ unsigned short Bs[128 * 72];

    const int tid = threadIdx.x;
    const int i0 = blockIdx.x * 128;

    const int wave = tid >> 6;
    const int lane = tid & 63;
    const int m16 = lane & 15;
    const int quad = lane >> 4;
    const int mr = (wave & 1) * 64;
    const int nc = (wave >> 1) * 64;

    f32x4 acc[4][4];
    #pragma unroll
    for (int a = 0; a < 4; ++a)
        #pragma unroll
        for (int b = 0; b < 4; ++b)
            acc[a][b] = (f32x4){0.f, 0.f, 0.f, 0.f};

    const int r0 = tid >> 3;
    const int kk = (tid & 7) * 8;

    for (int kc = 0; kc < 128; kc += 64) {
        if (kc) __syncthreads();
        #pragma unroll
        for (int it = 0; it < 4; ++it) {
            int r = r0 + it * 32;
            int gi_ = i0 + r;
            bf16x8 av = {0, 0, 0, 0, 0, 0, 0, 0};
            if (gi_ < M) av = *(const bf16x8*)(A + (size_t)gi_ * 128 + kc + kk);
            *(bf16x8*)&As[r * 72 + kk] = av;
            *(bf16x8*)&Bs[r * 72 + kk] = *(const bf16x8*)(W + (size_t)r * 128 + kc + kk);
        }
        __syncthreads();

        #pragma unroll
        for (int ks = 0; ks < 64; ks += 32) {
            bf16x8 af[4], bf_[4];
            #pragma unroll
            for (int rt = 0; rt < 4; ++rt)
                af[rt] = *(const bf16x8*)&As[(mr + rt * 16 + m16) * 72 + ks + quad * 8];
            #pragma unroll
            for (int ct = 0; ct < 4; ++ct)
                bf_[ct] = *(const bf16x8*)&Bs[(nc + ct * 16 + m16) * 72 + ks + quad * 8];
            #pragma unroll
            for (int rt = 0; rt < 4; ++rt)
                #pragma unroll
                for (int ct = 0; ct < 4; ++ct)
                    acc[rt][ct] = __builtin_amdgcn_mfma_f32_16x16x32_bf16(
                        af[rt], bf_[ct], acc[rt][ct], 0, 0, 0);
        }
    }

    #pragma unroll
    for (int rt = 0; rt < 4; ++rt) {
        #pragma unroll
        for (int r4 = 0; r4 < 4; ++r4) {
            int i = i0 + mr + rt * 16 + quad * 4 + r4;
            if (i >= M) continue;
            #pragma unroll
            for (int ct = 0; ct < 4; ++ct) {
                int j = nc + ct * 16 + m16;
                Cb[(size_t)i * 128 + j] = f2bf(acc[rt][ct][r4]);
            }
        }
    }
}

// ---------------- fused GRU: both GEMMs + gates + relu, no gi buffer ----------------
// Block = 64 rows x 384 cols, 4 waves (16 rows each). A staged in LDS; B (weights)
// read as fragments straight from global (L1/L2-resident, same for all blocks).
__global__ __launch_bounds__(256, 2) void gru_fused(const unsigned short* __restrict__ aggb,
                                                    const unsigned short* __restrict__ hb_in,
                                                    const unsigned short* __restrict__ Wih,
                                                    const unsigned short* __restrict__ Whh,
                                                    const float* __restrict__ bih,
                                                    const float* __restrict__ bhh,
                                                    float* __restrict__ h,
                                                    unsigned short* __restrict__ hb_out) {
    __shared__ unsigned short As_a[64 * 136];   // agg rows, K=128, pitch 136
    __shared__ unsigned short As_h[64 * 136];   // h rows

    const int tid = threadIdx.x;
    const int i0 = blockIdx.x * 64;
    const int wave = tid >> 6;
    const int lane = tid & 63;
    const int m16 = lane & 15;
    const int quad = lane >> 4;
    const int wrow = wave * 16;

    // stage A (both matrices), 16B chunks: 64 rows x 16 chunks = 1024 per matrix
    #pragma unroll
    for (int it = 0; it < 4; ++it) {
        int cid = it * 256 + tid;
        int r = cid >> 4;
        int c8 = (cid & 15) * 8;
        int gi_ = i0 + r;
        bf16x8 va = {0, 0, 0, 0, 0, 0, 0, 0};
        bf16x8 vh = {0, 0, 0, 0, 0, 0, 0, 0};
        if (gi_ < N_NODES) {
            va = *(const bf16x8*)(aggb + (size_t)gi_ * 128 + c8);
            vh = *(const bf16x8*)(hb_in + (size_t)gi_ * 128 + c8);
        }
        *(bf16x8*)&As_a[r * 136 + c8] = va;
        *(bf16x8*)&As_h[r * 136 + c8] = vh;
    }
    __syncthreads();

    // accumulators: rz[0..7]=r cols 0..127, rz[8..15]=z cols 128..255,
    // ni[0..7]=i_n cols 256..383, nh[0..7]=h_n cols 256..383
    f32x4 rz[16], ni[8], nh[8];
    #pragma unroll
    for (int i = 0; i < 16; ++i) rz[i] = (f32x4){0.f, 0.f, 0.f, 0.f};
    #pragma unroll
    for (int i = 0; i < 8; ++i) { ni[i] = (f32x4){0.f, 0.f, 0.f, 0.f}; nh[i] = (f32x4){0.f, 0.f, 0.f, 0.f}; }

    for (int ks = 0; ks < 4; ++ks) {
        const int k = ks * 32 + quad * 8;
        bf16x8 af_a = *(const bf16x8*)&As_a[(wrow + m16) * 136 + k];
        bf16x8 af_h = *(const bf16x8*)&As_h[(wrow + m16) * 136 + k];
        #pragma unroll
        for (int ct = 0; ct < 16; ++ct) {
            int j = ct * 16 + m16;
            bf16x8 b_ih = *(const bf16x8*)(Wih + (size_t)j * 128 + k);
            bf16x8 b_hh = *(const bf16x8*)(Whh + (size_t)j * 128 + k);
            rz[ct] = __builtin_amdgcn_mfma_f32_16x16x32_bf16(af_a, b_ih, rz[ct], 0, 0, 0);
            rz[ct] = __builtin_amdgcn_mfma_f32_16x16x32_bf16(af_h, b_hh, rz[ct], 0, 0, 0);
        }
        #pragma unroll
        for (int ct = 0; ct < 8; ++ct) {
            int j = 256 + ct * 16 + m16;
            bf16x8 b_ih = *(const bf16x8*)(Wih + (size_t)j * 128 + k);
            bf16x8 b_hh = *(const bf16x8*)(Whh + (size_t)j * 128 + k);
            ni[ct] = __builtin_amdgcn_mfma_f32_16x16x32_bf16(af_a, b_ih, ni[ct], 0, 0, 0);
            nh[ct] = __builtin_amdgcn_mfma_f32_16x16x32_bf16(af_h, b_hh, nh[ct], 0, 0, 0);
        }
    }

    // epilogue: gates. lane's cols: c = ct*16 + m16; rows: quad*4 + r4
    #pragma unroll
    for (int ct = 0; ct < 8; ++ct) {
        int c = ct * 16 + m16;
        float br = bih[c] + bhh[c];
        float bz = bih[128 + c] + bhh[128 + c];
        float bn_i = bih[256 + c];
        float bn_h = bhh[256 + c];
        #pragma unroll
        for (int r4 = 0; r4 < 4; ++r4) {
            int row = i0 + wrow + quad * 4 + r4;
            if (row >= N_NODES) continue;
            float r_pre = rz[ct][r4] + br;
            float z_pre = rz[8 + ct][r4] + bz;
            float in_ = ni[ct][r4] + bn_i;
            float hn_ = nh[ct][r4] + bn_h;
            float r = 1.f / (1.f + expf(-r_pre));
            float z = 1.f / (1.f + expf(-z_pre));
            float n = tanhf(in_ + r * hn_);
            float ho = h[(size_t)row * 128 + c];
            float o = (1.f - z) * n + z * ho;
            o = o > 0.f ? o : 0.f;
            h[(size_t)row * 128 + c] = o;
            hb_out[(size_t)row * 128 + c] = f2bf(o);
        }
    }
}

// ---------------- mean pool over sorted batch ----------------
__global__ __launch_bounds__(128) void pool_sorted(const float* __restrict__ h,
                                                   const int* __restrict__ batch,
                                                   float* __restrict__ hg) {
    int g = blockIdx.x;
    int c = threadIdx.x;
    int lo = 0, hi = N_NODES;
    while (lo < hi) { int mid = (lo + hi) >> 1; if (batch[mid] < g) lo = mid + 1; else hi = mid; }
    int start = lo;
    lo = start; hi = N_NODES;
    while (lo < hi) { int mid = (lo + hi) >> 1; if (batch[mid] < g + 1) lo = mid + 1; else hi = mid; }
    int end = lo;
    float s = 0.f;
    for (int i = start; i < end; ++i) s += h[(size_t)i * D + c];
    float cnt = (float)(end - start);
    hg[(size_t)g * D + c] = s / fmaxf(cnt, 1.f);
}

// ---------------- fc1 + elu ----------------
__global__ __launch_bounds__(128) void fc1_elu(const float* __restrict__ hg,
                                               const float* __restrict__ w,
                                               const float* __restrict__ b,
                                               float* __restrict__ z) {
    __shared__ float row[128];
    int g = blockIdx.x;
    int j = threadIdx.x;
    row[j] = hg[(size_t)g * 128 + j];
    __syncthreads();
    float acc = b[j];
    const float* wr = w + (size_t)j * 128;
    #pragma unroll 4
    for (int k = 0; k < 128; ++k) acc += row[k] * wr[k];
    z[(size_t)g * 128 + j] = acc > 0.f ? acc : (expf(acc) - 1.f);
}

// ---------------- fc2 ----------------
__global__ __launch_bounds__(64) void fc2_k(const float* __restrict__ z,
                                            const float* __restrict__ w,
                                            const float* __restrict__ b,
                                            float* __restrict__ logits) {
    __shared__ float row[128];
    int g = blockIdx.x;
    int t = threadIdx.x;
    row[t] = z[(size_t)g * 128 + t];
    row[t + 64] = z[(size_t)g * 128 + 64 + t];
    __syncthreads();
    if (t < N_CLASSES) {
        float acc = b[t];
        const float* wr = w + (size_t)t * 128;
        #pragma unroll 4
        for (int k = 0; k < 128; ++k) acc += row[k] * wr[k];
        logits[(size_t)g * N_CLASSES + t] = acc;
    }
}

// ---------------- log_softmax over axis 0 ----------------
__global__ __launch_bounds__(512) void logsoftmax_axis0(const float* __restrict__ logits,
                                                        float* __restrict__ out) {
    __shared__ float red[512];
    int c = blockIdx.x;
    int g = threadIdx.x;
    float x = logits[(size_t)g * N_CLASSES + c];
    red[g] = x;
    __syncthreads();
    for (int s = 256; s > 0; s >>= 1) {
        if (g < s) red[g] = fmaxf(red[g], red[g + s]);
        __syncthreads();
    }
    float mx = red[0];
    __syncthreads();
    red[g] = expf(x - mx);
    __syncthreads();
    for (int s = 256; s > 0; s >>= 1) {
        if (g < s) red[g] += red[g + s];
        __syncthreads();
    }
    float lse = mx + logf(red[0]);
    out[(size_t)g * N_CLASSES + c] = x - lse;
}

// ---------------- launch ----------------
extern "C" void kernel_launch(void* const* d_in, const int* in_sizes, int n_in,
                              void* d_out, int out_size, void* d_ws, size_t ws_size,
                              hipStream_t stream) {
    const float* h_in   = (const float*)d_in[0];
    const int*   eidx   = (const int*)d_in[1];
    const int*   batch  = (const int*)d_in[3];
    const float* Ws     = (const float*)d_in[4];
    const float* W_ih   = (const float*)d_in[5];
    const float* W_hh   = (const float*)d_in[6];
    const float* b_ih   = (const float*)d_in[7];
    const float* b_hh   = (const float*)d_in[8];
    const float* fc1_w  = (const float*)d_in[9];
    const float* fc1_b  = (const float*)d_in[10];
    const float* fc2_w  = (const float*)d_in[11];
    const float* fc2_b  = (const float*)d_in[12];
    float* out = (float*)d_out;

    char* ws = (char*)d_ws;
    size_t off = 0;
    auto alloc = [&](size_t bytes) {
        void* p = ws + off;
        off += (bytes + 255) & ~(size_t)255;
        return p;
    };
    float* h            = (float*)alloc((size_t)N_NODES * D * 4);
    unsigned short* hb  = (unsigned short*)alloc((size_t)N_NODES * D * 2);
    unsigned short* mb  = (unsigned short*)alloc((size_t)N_NODES * D * 2);
    unsigned short* aggb= (unsigned short*)alloc((size_t)N_NODES * D * 2);
    unsigned short* WsT_bf = (unsigned short*)alloc((size_t)N_LAYERS * D * D * 2);
    unsigned short* Wih_bf = (unsigned short*)alloc((size_t)N_LAYERS * 3 * D * D * 2);
    unsigned short* Whh_bf = (unsigned short*)alloc((size_t)N_LAYERS * 3 * D * D * 2);
    float* hg   = (float*)alloc((size_t)N_GRAPHS * D * 4);
    float* zb   = (float*)alloc((size_t)N_GRAPHS * D * 4);
    float* lgts = (float*)alloc((size_t)N_GRAPHS * N_CLASSES * 4);
    int* deg     = (int*)alloc((size_t)N_NODES * 4);
    int* row_ptr = (int*)alloc((size_t)(N_NODES + 1) * 4);
    int* pos     = (int*)alloc((size_t)N_NODES * 4);
    int* csr_src = (int*)alloc((size_t)N_EDGES * 4);
    int* bsum    = (int*)alloc((size_t)NBLK_SCAN * 4);
    int* boff    = (int*)alloc((size_t)NBLK_SCAN * 4);

    const int* src = eidx;
    const int* dst = eidx + N_EDGES;

    convert_h<<<(N_NODES * D + 255) / 256, 256, 0, stream>>>(h_in, h, hb);
    convert_weights<<<(N_LAYERS * 3 * D * D + 255) / 256, 256, 0, stream>>>(
        Ws, W_ih, W_hh, WsT_bf, Wih_bf, Whh_bf);

    // CSR build (edges static) — distributed scan
    fill_zero4<<<(N_NODES / 4 + 255) / 256, 256, 0, stream>>>((float4*)deg, N_NODES / 4);
    hist_dst<<<(N_EDGES + 255) / 256, 256, 0, stream>>>(dst, deg);
    block_sum<<<NBLK_SCAN, 256, 0, stream>>>(deg, bsum);
    scan_partials<<<1, 256, 0, stream>>>(bsum, boff, row_ptr);
    scan_final<<<NBLK_SCAN, 256, 0, stream>>>(deg, boff, row_ptr, pos);
    fill_csr<<<(N_EDGES + 255) / 256, 256, 0, stream>>>(src, dst, pos, csr_src);

    const int mtiles = (N_NODES + 127) / 128;   // 391
    const int gtiles = (N_NODES + 63) / 64;     // 782
    for (int l = 0; l < N_LAYERS; ++l) {
        gemm_m<<<mtiles, 256, 0, stream>>>(hb, WsT_bf + (size_t)l * D * D, mb, N_NODES);
        gather_agg<<<(N_NODES + 15) / 16, 256, 0, stream>>>(mb, row_ptr, csr_src, aggb);
        gru_fused<<<gtiles, 256, 0, stream>>>(
            aggb, hb, Wih_bf + (size_t)l * 3 * D * D, Whh_bf + (size_t)l * 3 * D * D,
            b_ih + (size_t)l * 384, b_hh + (size_t)l * 384, h, hb);
    }

    pool_sorted<<<N_GRAPHS, 128, 0, stream>>>(h, batch, hg);
    fc1_elu<<<N_GRAPHS, 128, 0, stream>>>(hg, fc1_w, fc1_b, zb);
    fc2_k<<<N_GRAPHS, 64, 0, stream>>>(zb, fc2_w, fc2_b, lgts);
    logsoftmax_axis0<<<N_CLASSES, 512, 0, stream>>>(lgts, out);
}

// Round 5
// 681.185 us; speedup vs baseline: 8.4643x; 1.2924x over previous
//
#include <hip/hip_runtime.h>
#include <math.h>

#define N_NODES 50000
#define N_EDGES 600000
#define D 128
#define N_GRAPHS 512
#define N_CLASSES 10
#define N_LAYERS 4
#define NBLK_SCAN 196   // ceil(50000/256)

typedef __attribute__((ext_vector_type(8))) short bf16x8;
typedef __attribute__((ext_vector_type(4))) float f32x4;

__device__ inline unsigned short f2bf(float f) {
    union { float f; unsigned int u; } v; v.f = f;
    unsigned int r = (v.u + 0x7fffu + ((v.u >> 16) & 1u)) >> 16;
    return (unsigned short)r;
}
__device__ inline float bf2f(unsigned short u) {
    union { unsigned int u; float f; } v; v.u = ((unsigned int)u) << 16;
    return v.f;
}

// ---------------- zero fill ----------------
__global__ __launch_bounds__(256) void fill_zero4(float4* p, int n4) {
    int i = blockIdx.x * 256 + threadIdx.x;
    if (i < n4) p[i] = make_float4(0.f, 0.f, 0.f, 0.f);
}

// ---------------- weight conversion: fp32 -> bf16 ----------------
// Wih_bf/Whh_bf: straight copy [L][384][128]. Ws_bf: straight copy [L][128][128].
__global__ __launch_bounds__(256) void convert_weights(const float* __restrict__ Ws,
                                                       const float* __restrict__ Wih,
                                                       const float* __restrict__ Whh,
                                                       unsigned short* __restrict__ Ws_bf,
                                                       unsigned short* __restrict__ Wih_bf,
                                                       unsigned short* __restrict__ Whh_bf) {
    int idx = blockIdx.x * 256 + threadIdx.x;
    if (idx < N_LAYERS * D * D) Ws_bf[idx] = f2bf(Ws[idx]);
    if (idx < N_LAYERS * 3 * D * D) {
        Wih_bf[idx] = f2bf(Wih[idx]);
        Whh_bf[idx] = f2bf(Whh[idx]);
    }
}

// ---------------- h init: fp32 copy + bf16 mirror into cat[:,128:256] ----------------
__global__ __launch_bounds__(256) void convert_h(const float* __restrict__ h_in,
                                                 float* __restrict__ h,
                                                 unsigned short* __restrict__ cat) {
    int idx = blockIdx.x * 256 + threadIdx.x;
    if (idx >= N_NODES * D) return;
    int i = idx >> 7;
    int c = idx & 127;
    float v = h_in[idx];
    h[idx] = v;
    cat[(size_t)i * 256 + 128 + c] = f2bf(v);
}

// ---------------- build B_cat[l][512][256] from W' (384x128) and Whh ----------------
// j<256 (r,z summed):   k<128 -> W'[l][j][k],       k>=128 -> Whh[l][j][k-128]
// 256<=j<384 (i_n):     k<128 -> W'[l][j][k],       k>=128 -> 0
// 384<=j<512 (h_n):     k<128 -> 0,                 k>=128 -> Whh[l][j-128][k-128]
__global__ __launch_bounds__(256) void build_bcat(const unsigned short* __restrict__ Wp,
                                                  const unsigned short* __restrict__ Whh,
                                                  unsigned short* __restrict__ Bcat) {
    int idx = blockIdx.x * 256 + threadIdx.x;   // L*512*256
    if (idx >= N_LAYERS * 512 * 256) return;
    int l = idx >> 17;
    int rem = idx & 131071;
    int j = rem >> 8;
    int k = rem & 255;
    unsigned short v = 0;
    if (j < 256) {
        v = (k < 128) ? Wp[((size_t)l * 384 + j) * 128 + k]
                      : Whh[((size_t)l * 384 + j) * 128 + (k - 128)];
    } else if (j < 384) {
        v = (k < 128) ? Wp[((size_t)l * 384 + j) * 128 + k] : (unsigned short)0;
    } else {
        v = (k >= 128) ? Whh[((size_t)l * 384 + (j - 128)) * 128 + (k - 128)] : (unsigned short)0;
    }
    Bcat[idx] = v;
}

// ---------------- CSR build ----------------
__global__ __launch_bounds__(256) void hist_dst(const int* __restrict__ dst,
                                                int* __restrict__ deg) {
    int e = blockIdx.x * 256 + threadIdx.x;
    if (e < N_EDGES) atomicAdd(&deg[dst[e]], 1);
}

__global__ __launch_bounds__(256) void block_sum(const int* __restrict__ deg,
                                                 int* __restrict__ bsum) {
    __shared__ int s[256];
    int t = threadIdx.x;
    int i = blockIdx.x * 256 + t;
    s[t] = (i < N_NODES) ? deg[i] : 0;
    __syncthreads();
    for (int o = 128; o > 0; o >>= 1) {
        if (t < o) s[t] += s[t + o];
        __syncthreads();
    }
    if (t == 0) bsum[blockIdx.x] = s[0];
}

__global__ __launch_bounds__(256) void scan_partials(const int* __restrict__ bsum,
                                                     int* __restrict__ boff,
                                                     int* __restrict__ row_ptr) {
    __shared__ int s[256];
    int t = threadIdx.x;
    int v = (t < NBLK_SCAN) ? bsum[t] : 0;
    s[t] = v;
    __syncthreads();
    for (int o = 1; o < 256; o <<= 1) {
        int x = (t >= o) ? s[t - o] : 0;
        __syncthreads();
        s[t] += x;
        __syncthreads();
    }
    if (t < NBLK_SCAN) boff[t] = s[t] - v;   // exclusive
    if (t == 255) row_ptr[N_NODES] = s[255];
}

__global__ __launch_bounds__(256) void scan_final(const int* __restrict__ deg,
                                                  const int* __restrict__ boff,
                                                  int* __restrict__ row_ptr,
                                                  int* __restrict__ pos) {
    __shared__ int s[256];
    int t = threadIdx.x;
    int i = blockIdx.x * 256 + t;
    int v = (i < N_NODES) ? deg[i] : 0;
    s[t] = v;
    __syncthreads();
    for (int o = 1; o < 256; o <<= 1) {
        int x = (t >= o) ? s[t - o] : 0;
        __syncthreads();
        s[t] += x;
        __syncthreads();
    }
    int excl = s[t] - v + boff[blockIdx.x];
    if (i < N_NODES) {
        row_ptr[i] = excl;
        pos[i] = excl;
    }
}

__global__ __launch_bounds__(256) void fill_csr(const int* __restrict__ src,
                                                const int* __restrict__ dst,
                                                int* __restrict__ pos,
                                                int* __restrict__ csr_src) {
    int e = blockIdx.x * 256 + threadIdx.x;
    if (e >= N_EDGES) return;
    int p = atomicAdd(&pos[dst[e]], 1);
    csr_src[p] = src[e];
}

// ---------------- gather: cat[n, 0:128] = sum_{e:dst=n} cat[src[e], 128:256] ----------------
__global__ __launch_bounds__(256) void gather_agg(unsigned short* __restrict__ cat,
                                                  const int* __restrict__ row_ptr,
                                                  const int* __restrict__ csr_src) {
    int t = threadIdx.x;
    int node = blockIdx.x * 16 + (t >> 4);
    int c8 = (t & 15) * 8;
    if (node >= N_NODES) return;
    int b = row_ptr[node];
    int e2 = row_ptr[node + 1];
    float acc[8] = {};
    for (int e = b; e < e2; ++e) {
        int s = csr_src[e];
        bf16x8 v = *(const bf16x8*)(cat + (size_t)s * 256 + 128 + c8);
        #pragma unroll
        for (int j = 0; j < 8; ++j) acc[j] += bf2f((unsigned short)v[j]);
    }
    bf16x8 ov;
    #pragma unroll
    for (int j = 0; j < 8; ++j) ov[j] = (short)f2bf(acc[j]);
    *(bf16x8*)(cat + (size_t)node * 256 + c8) = ov;
}

// ---------------- generic bf16 MFMA GEMM: out[i,j] = bf16( sum_k A[i,k]*W[j,k] ) ----------------
// 128x128 output tile, 4 waves. A pitch Ap, W pitch Wp (row-major [j][k]), out pitch Op.
// K = Kd (multiple of 64). Rows of W (j0+r, r<128) must be valid for all grid.y tiles.
__global__ __launch_bounds__(256) void gemm_bf16(const unsigned short* __restrict__ A, int Ap,
                                                 const unsigned short* __restrict__ W, int Wp,
                                                 unsigned short* __restrict__ out, int Op,
                                                 int M, int Kd) {
    __shared__ unsigned short As[128 * 72];
    __shared__ unsigned short Bs[128 * 72];

    const int tid = threadIdx.x;
    const int i0 = blockIdx.x * 128;
    const int j0 = blockIdx.y * 128;

    const int wave = tid >> 6;
    const int lane = tid & 63;
    const int m16 = lane & 15;
    const int quad = lane >> 4;
    const int mr = (wave & 1) * 64;
    const int nc = (wave >> 1) * 64;

    f32x4 acc[4][4];
    #pragma unroll
    for (int a = 0; a < 4; ++a)
        #pragma unroll
        for (int b = 0; b < 4; ++b)
            acc[a][b] = (f32x4){0.f, 0.f, 0.f, 0.f};

    const int r0 = tid >> 3;          // 0..31
    const int kk = (tid & 7) * 8;     // 0..56

    for (int kc = 0; kc < Kd; kc += 64) {
        if (kc) __syncthreads();
        #pragma unroll
        for (int it = 0; it < 4; ++it) {
            int r = r0 + it * 32;
            int gi_ = i0 + r;
            bf16x8 av = {0, 0, 0, 0, 0, 0, 0, 0};
            if (gi_ < M) av = *(const bf16x8*)(A + (size_t)gi_ * Ap + kc + kk);
            *(bf16x8*)&As[r * 72 + kk] = av;
            *(bf16x8*)&Bs[r * 72 + kk] = *(const bf16x8*)(W + (size_t)(j0 + r) * Wp + kc + kk);
        }
        __syncthreads();

        #pragma unroll
        for (int ks = 0; ks < 64; ks += 32) {
            bf16x8 af[4], bf_[4];
            #pragma unroll
            for (int rt = 0; rt < 4; ++rt)
                af[rt] = *(const bf16x8*)&As[(mr + rt * 16 + m16) * 72 + ks + quad * 8];
            #pragma unroll
            for (int ct = 0; ct < 4; ++ct)
                bf_[ct] = *(const bf16x8*)&Bs[(nc + ct * 16 + m16) * 72 + ks + quad * 8];
            #pragma unroll
            for (int rt = 0; rt < 4; ++rt)
                #pragma unroll
                for (int ct = 0; ct < 4; ++ct)
                    acc[rt][ct] = __builtin_amdgcn_mfma_f32_16x16x32_bf16(
                        af[rt], bf_[ct], acc[rt][ct], 0, 0, 0);
        }
    }

    #pragma unroll
    for (int rt = 0; rt < 4; ++rt) {
        #pragma unroll
        for (int r4 = 0; r4 < 4; ++r4) {
            int i = i0 + mr + rt * 16 + quad * 4 + r4;
            if (i >= M) continue;
            #pragma unroll
            for (int ct = 0; ct < 4; ++ct) {
                int j = j0 + nc + ct * 16 + m16;
                out[(size_t)i * Op + j] = f2bf(acc[rt][ct][r4]);
            }
        }
    }
}

// ---------------- GRU gates + relu from bf16 gi; writes h fp32 + bf16 into cat ----------------
__global__ __launch_bounds__(256) void gru_gates(const unsigned short* __restrict__ gi,
                                                 const float* __restrict__ bih,
                                                 const float* __restrict__ bhh,
                                                 float* __restrict__ h,
                                                 unsigned short* __restrict__ cat) {
    int idx = blockIdx.x * 256 + threadIdx.x;   // N*32
    if (idx >= N_NODES * 32) return;
    int i = idx >> 5;
    int c = (idx & 31) * 4;
    size_t base = (size_t)i * 512;
    ushort4 vr = *(const ushort4*)(gi + base + c);
    ushort4 vz = *(const ushort4*)(gi + base + 128 + c);
    ushort4 vn = *(const ushort4*)(gi + base + 256 + c);
    ushort4 vh = *(const ushort4*)(gi + base + 384 + c);
    float4 ho = *(const float4*)(h + (size_t)i * 128 + c);
    float4 hv;
    #pragma unroll
    for (int q = 0; q < 4; ++q) {
        int cc = c + q;
        float r_pre = bf2f(q == 0 ? vr.x : q == 1 ? vr.y : q == 2 ? vr.z : vr.w) + bih[cc] + bhh[cc];
        float z_pre = bf2f(q == 0 ? vz.x : q == 1 ? vz.y : q == 2 ? vz.z : vz.w) + bih[128 + cc] + bhh[128 + cc];
        float i_n   = bf2f(q == 0 ? vn.x : q == 1 ? vn.y : q == 2 ? vn.z : vn.w) + bih[256 + cc];
        float h_n   = bf2f(q == 0 ? vh.x : q == 1 ? vh.y : q == 2 ? vh.z : vh.w) + bhh[256 + cc];
        float hold = q == 0 ? ho.x : q == 1 ? ho.y : q == 2 ? ho.z : ho.w;
        float r = 1.f / (1.f + expf(-r_pre));
        float z = 1.f / (1.f + expf(-z_pre));
        float n = tanhf(i_n + r * h_n);
        float o = (1.f - z) * n + z * hold;
        o = o > 0.f ? o : 0.f;
        if (q == 0) hv.x = o; else if (q == 1) hv.y = o; else if (q == 2) hv.z = o; else hv.w = o;
    }
    *(float4*)(h + (size_t)i * 128 + c) = hv;
    ushort4 hb4;
    hb4.x = f2bf(hv.x); hb4.y = f2bf(hv.y); hb4.z = f2bf(hv.z); hb4.w = f2bf(hv.w);
    *(ushort4*)(cat + (size_t)i * 256 + 128 + c) = hb4;
}

// ---------------- mean pool over sorted batch ----------------
__global__ __launch_bounds__(128) void pool_sorted(const float* __restrict__ h,
                                                   const int* __restrict__ batch,
                                                   float* __restrict__ hg) {
    int g = blockIdx.x;
    int c = threadIdx.x;
    int lo = 0, hi = N_NODES;
    while (lo < hi) { int mid = (lo + hi) >> 1; if (batch[mid] < g) lo = mid + 1; else hi = mid; }
    int start = lo;
    lo = start; hi = N_NODES;
    while (lo < hi) { int mid = (lo + hi) >> 1; if (batch[mid] < g + 1) lo = mid + 1; else hi = mid; }
    int end = lo;
    float s = 0.f;
    for (int i = start; i < end; ++i) s += h[(size_t)i * D + c];
    float cnt = (float)(end - start);
    hg[(size_t)g * D + c] = s / fmaxf(cnt, 1.f);
}

// ---------------- fc1 + elu ----------------
__global__ __launch_bounds__(128) void fc1_elu(const float* __restrict__ hg,
                                               const float* __restrict__ w,
                                               const float* __restrict__ b,
                                               float* __restrict__ z) {
    __shared__ float row[128];
    int g = blockIdx.x;
    int j = threadIdx.x;
    row[j] = hg[(size_t)g * 128 + j];
    __syncthreads();
    float acc = b[j];
    const float* wr = w + (size_t)j * 128;
    #pragma unroll 4
    for (int k = 0; k < 128; ++k) acc += row[k] * wr[k];
    z[(size_t)g * 128 + j] = acc > 0.f ? acc : (expf(acc) - 1.f);
}

// ---------------- fc2 ----------------
__global__ __launch_bounds__(64) void fc2_k(const float* __restrict__ z,
                                            const float* __restrict__ w,
                                            const float* __restrict__ b,
                                            float* __restrict__ logits) {
    __shared__ float row[128];
    int g = blockIdx.x;
    int t = threadIdx.x;
    row[t] = z[(size_t)g * 128 + t];
    row[t + 64] = z[(size_t)g * 128 + 64 + t];
    __syncthreads();
    if (t < N_CLASSES) {
        float acc = b[t];
        const float* wr = w + (size_t)t * 128;
        #pragma unroll 4
        for (int k = 0; k < 128; ++k) acc += row[k] * wr[k];
        logits[(size_t)g * N_CLASSES + t] = acc;
    }
}

// ---------------- log_softmax over axis 0 ----------------
__global__ __launch_bounds__(512) void logsoftmax_axis0(const float* __restrict__ logits,
                                                        float* __restrict__ out) {
    __shared__ float red[512];
    int c = blockIdx.x;
    int g = threadIdx.x;
    float x = logits[(size_t)g * N_CLASSES + c];
    red[g] = x;
    __syncthreads();
    for (int s = 256; s > 0; s >>= 1) {
        if (g < s) red[g] = fmaxf(red[g], red[g + s]);
        __syncthreads();
    }
    float mx = red[0];
    __syncthreads();
    red[g] = expf(x - mx);
    __syncthreads();
    for (int s = 256; s > 0; s >>= 1) {
        if (g < s) red[g] += red[g + s];
        __syncthreads();
    }
    float lse = mx + logf(red[0]);
    out[(size_t)g * N_CLASSES + c] = x - lse;
}

// ---------------- launch ----------------
extern "C" void kernel_launch(void* const* d_in, const int* in_sizes, int n_in,
                              void* d_out, int out_size, void* d_ws, size_t ws_size,
                              hipStream_t stream) {
    const float* h_in   = (const float*)d_in[0];
    const int*   eidx   = (const int*)d_in[1];
    const int*   batch  = (const int*)d_in[3];
    const float* Ws     = (const float*)d_in[4];
    const float* W_ih   = (const float*)d_in[5];
    const float* W_hh   = (const float*)d_in[6];
    const float* b_ih   = (const float*)d_in[7];
    const float* b_hh   = (const float*)d_in[8];
    const float* fc1_w  = (const float*)d_in[9];
    const float* fc1_b  = (const float*)d_in[10];
    const float* fc2_w  = (const float*)d_in[11];
    const float* fc2_b  = (const float*)d_in[12];
    float* out = (float*)d_out;

    char* ws = (char*)d_ws;
    size_t off = 0;
    auto alloc = [&](size_t bytes) {
        void* p = ws + off;
        off += (bytes + 255) & ~(size_t)255;
        return p;
    };
    float* h             = (float*)alloc((size_t)N_NODES * D * 4);
    unsigned short* cat  = (unsigned short*)alloc((size_t)N_NODES * 256 * 2);  // [agg | h] bf16
    unsigned short* gi   = (unsigned short*)alloc((size_t)N_NODES * 512 * 2);  // gemm out bf16
    unsigned short* Ws_bf  = (unsigned short*)alloc((size_t)N_LAYERS * D * D * 2);
    unsigned short* Wih_bf = (unsigned short*)alloc((size_t)N_LAYERS * 3 * D * D * 2);
    unsigned short* Whh_bf = (unsigned short*)alloc((size_t)N_LAYERS * 3 * D * D * 2);
    unsigned short* Wp_bf  = (unsigned short*)alloc((size_t)N_LAYERS * 3 * D * D * 2);  // Wih @ Ws^T
    unsigned short* Bcat   = (unsigned short*)alloc((size_t)N_LAYERS * 512 * 256 * 2);
    float* hg   = (float*)alloc((size_t)N_GRAPHS * D * 4);
    float* zb   = (float*)alloc((size_t)N_GRAPHS * D * 4);
    float* lgts = (float*)alloc((size_t)N_GRAPHS * N_CLASSES * 4);
    int* deg     = (int*)alloc((size_t)N_NODES * 4);
    int* row_ptr = (int*)alloc((size_t)(N_NODES + 1) * 4);
    int* pos     = (int*)alloc((size_t)N_NODES * 4);
    int* csr_src = (int*)alloc((size_t)N_EDGES * 4);
    int* bsum    = (int*)alloc((size_t)NBLK_SCAN * 4);
    int* boff    = (int*)alloc((size_t)NBLK_SCAN * 4);

    const int* src = eidx;
    const int* dst = eidx + N_EDGES;

    convert_h<<<(N_NODES * D + 255) / 256, 256, 0, stream>>>(h_in, h, cat);
    convert_weights<<<(N_LAYERS * 3 * D * D + 255) / 256, 256, 0, stream>>>(
        Ws, W_ih, W_hh, Ws_bf, Wih_bf, Whh_bf);

    // W'_l = Wih_l @ Ws_l^T : out[j][k] = sum_t Wih[j][t] * Ws[k][t]
    for (int l = 0; l < N_LAYERS; ++l) {
        gemm_bf16<<<dim3(3, 1), 256, 0, stream>>>(
            Wih_bf + (size_t)l * 384 * 128, 128,
            Ws_bf + (size_t)l * 128 * 128, 128,
            Wp_bf + (size_t)l * 384 * 128, 128, 384, 128);
    }
    build_bcat<<<(N_LAYERS * 512 * 256 + 255) / 256, 256, 0, stream>>>(Wp_bf, Whh_bf, Bcat);

    // CSR build (edges static) — distributed scan
    fill_zero4<<<(N_NODES / 4 + 255) / 256, 256, 0, stream>>>((float4*)deg, N_NODES / 4);
    hist_dst<<<(N_EDGES + 255) / 256, 256, 0, stream>>>(dst, deg);
    block_sum<<<NBLK_SCAN, 256, 0, stream>>>(deg, bsum);
    scan_partials<<<1, 256, 0, stream>>>(bsum, boff, row_ptr);
    scan_final<<<NBLK_SCAN, 256, 0, stream>>>(deg, boff, row_ptr, pos);
    fill_csr<<<(N_EDGES + 255) / 256, 256, 0, stream>>>(src, dst, pos, csr_src);

    const int mtiles = (N_NODES + 127) / 128;   // 391
    for (int l = 0; l < N_LAYERS; ++l) {
        // cat[:,0:128] = gather of cat[:,128:256]  (agg_h)
        gather_agg<<<(N_NODES + 15) / 16, 256, 0, stream>>>(cat, row_ptr, csr_src);
        // gi = cat @ Bcat_l^T   (K=256, N=512)
        gemm_bf16<<<dim3(mtiles, 4), 256, 0, stream>>>(
            cat, 256, Bcat + (size_t)l * 512 * 256, 256, gi, 512, N_NODES, 256);
        // gates + relu -> h fp32, cat[:,128:256] bf16
        gru_gates<<<(N_NODES * 32 + 255) / 256, 256, 0, stream>>>(
            gi, b_ih + (size_t)l * 384, b_hh + (size_t)l * 384, h, cat);
    }

    pool_sorted<<<N_GRAPHS, 128, 0, stream>>>(h, batch, hg);
    fc1_elu<<<N_GRAPHS, 128, 0, stream>>>(hg, fc1_w, fc1_b, zb);
    fc2_k<<<N_GRAPHS, 64, 0, stream>>>(zb, fc2_w, fc2_b, lgts);
    logsoftmax_axis0<<<N_CLASSES, 512, 0, stream>>>(lgts, out);
}

// Round 6
// 548.281 us; speedup vs baseline: 10.5161x; 1.2424x over previous
//
#include <hip/hip_runtime.h>
#include <math.h>

#define N_NODES 50000
#define N_EDGES 600000
#define D 128
#define N_GRAPHS 512
#define N_CLASSES 10
#define N_LAYERS 4
#define NBLK_SCAN 196   // ceil(50000/256)

typedef __attribute__((ext_vector_type(8))) short bf16x8;
typedef __attribute__((ext_vector_type(4))) float f32x4;

__device__ inline unsigned short f2bf(float f) {
    union { float f; unsigned int u; } v; v.f = f;
    unsigned int r = (v.u + 0x7fffu + ((v.u >> 16) & 1u)) >> 16;
    return (unsigned short)r;
}
__device__ inline float bf2f(unsigned short u) {
    union { unsigned int u; float f; } v; v.u = ((unsigned int)u) << 16;
    return v.f;
}

// ---------------- zero fill ----------------
__global__ __launch_bounds__(256) void fill_zero4(float4* p, int n4) {
    int i = blockIdx.x * 256 + threadIdx.x;
    if (i < n4) p[i] = make_float4(0.f, 0.f, 0.f, 0.f);
}

// ---------------- weight conversion: fp32 -> bf16 ----------------
__global__ __launch_bounds__(256) void convert_weights(const float* __restrict__ Ws,
                                                       const float* __restrict__ Wih,
                                                       const float* __restrict__ Whh,
                                                       unsigned short* __restrict__ Ws_bf,
                                                       unsigned short* __restrict__ Wih_bf,
                                                       unsigned short* __restrict__ Whh_bf) {
    int idx = blockIdx.x * 256 + threadIdx.x;
    if (idx < N_LAYERS * D * D) Ws_bf[idx] = f2bf(Ws[idx]);
    if (idx < N_LAYERS * 3 * D * D) {
        Wih_bf[idx] = f2bf(Wih[idx]);
        Whh_bf[idx] = f2bf(Whh[idx]);
    }
}

// ---------------- combined bias table: [L][512] ----------------
// j<128: bih_r+bhh_r ; 128..256: bih_z+bhh_z ; 256..384: bih_n ; 384..512: bhh_n
__global__ __launch_bounds__(256) void combine_bias(const float* __restrict__ bih,
                                                    const float* __restrict__ bhh,
                                                    float* __restrict__ bc) {
    int idx = blockIdx.x * 256 + threadIdx.x;   // L*512
    if (idx >= N_LAYERS * 512) return;
    int l = idx >> 9;
    int j = idx & 511;
    const float* bi = bih + (size_t)l * 384;
    const float* bh = bhh + (size_t)l * 384;
    float v;
    if (j < 256) v = bi[j] + bh[j];
    else if (j < 384) v = bi[j];
    else v = bh[j - 128];
    bc[idx] = v;
}

// ---------------- h init: fp32 copy + bf16 mirror into cat[:,128:256] ----------------
__global__ __launch_bounds__(256) void convert_h(const float* __restrict__ h_in,
                                                 float* __restrict__ h,
                                                 unsigned short* __restrict__ cat) {
    int idx = blockIdx.x * 256 + threadIdx.x;
    if (idx >= N_NODES * D) return;
    int i = idx >> 7;
    int c = idx & 127;
    float v = h_in[idx];
    h[idx] = v;
    cat[(size_t)i * 256 + 128 + c] = f2bf(v);
}

// ---------------- build B_cat[l][512][256] from W' (384x128) and Whh ----------------
__global__ __launch_bounds__(256) void build_bcat(const unsigned short* __restrict__ Wp,
                                                  const unsigned short* __restrict__ Whh,
                                                  unsigned short* __restrict__ Bcat) {
    int idx = blockIdx.x * 256 + threadIdx.x;   // L*512*256
    if (idx >= N_LAYERS * 512 * 256) return;
    int l = idx >> 17;
    int rem = idx & 131071;
    int j = rem >> 8;
    int k = rem & 255;
    unsigned short v = 0;
    if (j < 256) {
        v = (k < 128) ? Wp[((size_t)l * 384 + j) * 128 + k]
                      : Whh[((size_t)l * 384 + j) * 128 + (k - 128)];
    } else if (j < 384) {
        v = (k < 128) ? Wp[((size_t)l * 384 + j) * 128 + k] : (unsigned short)0;
    } else {
        v = (k >= 128) ? Whh[((size_t)l * 384 + (j - 128)) * 128 + (k - 128)] : (unsigned short)0;
    }
    Bcat[idx] = v;
}

// ---------------- CSR build ----------------
__global__ __launch_bounds__(256) void hist_dst(const int* __restrict__ dst,
                                                int* __restrict__ deg) {
    int e = blockIdx.x * 256 + threadIdx.x;
    if (e < N_EDGES) atomicAdd(&deg[dst[e]], 1);
}

__global__ __launch_bounds__(256) void block_sum(const int* __restrict__ deg,
                                                 int* __restrict__ bsum) {
    __shared__ int s[256];
    int t = threadIdx.x;
    int i = blockIdx.x * 256 + t;
    s[t] = (i < N_NODES) ? deg[i] : 0;
    __syncthreads();
    for (int o = 128; o > 0; o >>= 1) {
        if (t < o) s[t] += s[t + o];
        __syncthreads();
    }
    if (t == 0) bsum[blockIdx.x] = s[0];
}

__global__ __launch_bounds__(256) void scan_partials(const int* __restrict__ bsum,
                                                     int* __restrict__ boff,
                                                     int* __restrict__ row_ptr) {
    __shared__ int s[256];
    int t = threadIdx.x;
    int v = (t < NBLK_SCAN) ? bsum[t] : 0;
    s[t] = v;
    __syncthreads();
    for (int o = 1; o < 256; o <<= 1) {
        int x = (t >= o) ? s[t - o] : 0;
        __syncthreads();
        s[t] += x;
        __syncthreads();
    }
    if (t < NBLK_SCAN) boff[t] = s[t] - v;   // exclusive
    if (t == 255) row_ptr[N_NODES] = s[255];
}

__global__ __launch_bounds__(256) void scan_final(const int* __restrict__ deg,
                                                  const int* __restrict__ boff,
                                                  int* __restrict__ row_ptr,
                                                  int* __restrict__ pos) {
    __shared__ int s[256];
    int t = threadIdx.x;
    int i = blockIdx.x * 256 + t;
    int v = (i < N_NODES) ? deg[i] : 0;
    s[t] = v;
    __syncthreads();
    for (int o = 1; o < 256; o <<= 1) {
        int x = (t >= o) ? s[t - o] : 0;
        __syncthreads();
        s[t] += x;
        __syncthreads();
    }
    int excl = s[t] - v + boff[blockIdx.x];
    if (i < N_NODES) {
        row_ptr[i] = excl;
        pos[i] = excl;
    }
}

__global__ __launch_bounds__(256) void fill_csr(const int* __restrict__ src,
                                                const int* __restrict__ dst,
                                                int* __restrict__ pos,
                                                int* __restrict__ csr_src) {
    int e = blockIdx.x * 256 + threadIdx.x;
    if (e >= N_EDGES) return;
    int p = atomicAdd(&pos[dst[e]], 1);
    csr_src[p] = src[e];
}

// ---------------- gather: cat[n, 0:128] = sum_{e:dst=n} cat[src[e], 128:256] ----------------
__global__ __launch_bounds__(256) void gather_agg(unsigned short* __restrict__ cat,
                                                  const int* __restrict__ row_ptr,
                                                  const int* __restrict__ csr_src) {
    int t = threadIdx.x;
    int node = blockIdx.x * 16 + (t >> 4);
    int c8 = (t & 15) * 8;
    if (node >= N_NODES) return;
    int b = row_ptr[node];
    int e2 = row_ptr[node + 1];
    float acc0[8] = {}, acc1[8] = {};
    int e = b;
    for (; e + 2 <= e2; e += 2) {
        int s0 = csr_src[e];
        int s1 = csr_src[e + 1];
        bf16x8 v0 = *(const bf16x8*)(cat + (size_t)s0 * 256 + 128 + c8);
        bf16x8 v1 = *(const bf16x8*)(cat + (size_t)s1 * 256 + 128 + c8);
        #pragma unroll
        for (int j = 0; j < 8; ++j) {
            acc0[j] += bf2f((unsigned short)v0[j]);
            acc1[j] += bf2f((unsigned short)v1[j]);
        }
    }
    if (e < e2) {
        int s0 = csr_src[e];
        bf16x8 v0 = *(const bf16x8*)(cat + (size_t)s0 * 256 + 128 + c8);
        #pragma unroll
        for (int j = 0; j < 8; ++j) acc0[j] += bf2f((unsigned short)v0[j]);
    }
    bf16x8 ov;
    #pragma unroll
    for (int j = 0; j < 8; ++j) ov[j] = (short)f2bf(acc0[j] + acc1[j]);
    *(bf16x8*)(cat + (size_t)node * 256 + c8) = ov;
}

// ---------------- generic bf16 MFMA GEMM (batched over blockIdx.z) ----------------
// out[i,j] = bf16( sum_k A[i,k]*W[j,k] ); layer strides lsA/lsW/lsO in elements.
__global__ __launch_bounds__(256) void gemm_bf16(const unsigned short* __restrict__ A, int Ap,
                                                 const unsigned short* __restrict__ W, int Wp,
                                                 unsigned short* __restrict__ out, int Op,
                                                 int M, int Kd,
                                                 size_t lsA, size_t lsW, size_t lsO) {
    A += (size_t)blockIdx.z * lsA;
    W += (size_t)blockIdx.z * lsW;
    out += (size_t)blockIdx.z * lsO;

    __shared__ unsigned short As[128 * 72];
    __shared__ unsigned short Bs[128 * 72];

    const int tid = threadIdx.x;
    const int i0 = blockIdx.x * 128;
    const int j0 = blockIdx.y * 128;

    const int wave = tid >> 6;
    const int lane = tid & 63;
    const int m16 = lane & 15;
    const int quad = lane >> 4;
    const int mr = (wave & 1) * 64;
    const int nc = (wave >> 1) * 64;

    f32x4 acc[4][4];
    #pragma unroll
    for (int a = 0; a < 4; ++a)
        #pragma unroll
        for (int b = 0; b < 4; ++b)
            acc[a][b] = (f32x4){0.f, 0.f, 0.f, 0.f};

    const int r0 = tid >> 3;          // 0..31
    const int kk = (tid & 7) * 8;     // 0..56

    for (int kc = 0; kc < Kd; kc += 64) {
        if (kc) __syncthreads();
        #pragma unroll
        for (int it = 0; it < 4; ++it) {
            int r = r0 + it * 32;
            int gi_ = i0 + r;
            bf16x8 av = {0, 0, 0, 0, 0, 0, 0, 0};
            if (gi_ < M) av = *(const bf16x8*)(A + (size_t)gi_ * Ap + kc + kk);
            *(bf16x8*)&As[r * 72 + kk] = av;
            *(bf16x8*)&Bs[r * 72 + kk] = *(const bf16x8*)(W + (size_t)(j0 + r) * Wp + kc + kk);
        }
        __syncthreads();

        #pragma unroll
        for (int ks = 0; ks < 64; ks += 32) {
            bf16x8 af[4], bf_[4];
            #pragma unroll
            for (int rt = 0; rt < 4; ++rt)
                af[rt] = *(const bf16x8*)&As[(mr + rt * 16 + m16) * 72 + ks + quad * 8];
            #pragma unroll
            for (int ct = 0; ct < 4; ++ct)
                bf_[ct] = *(const bf16x8*)&Bs[(nc + ct * 16 + m16) * 72 + ks + quad * 8];
            #pragma unroll
            for (int rt = 0; rt < 4; ++rt)
                #pragma unroll
                for (int ct = 0; ct < 4; ++ct)
                    acc[rt][ct] = __builtin_amdgcn_mfma_f32_16x16x32_bf16(
                        af[rt], bf_[ct], acc[rt][ct], 0, 0, 0);
        }
    }

    #pragma unroll
    for (int rt = 0; rt < 4; ++rt) {
        #pragma unroll
        for (int r4 = 0; r4 < 4; ++r4) {
            int i = i0 + mr + rt * 16 + quad * 4 + r4;
            if (i >= M) continue;
            #pragma unroll
            for (int ct = 0; ct < 4; ++ct) {
                int j = j0 + nc + ct * 16 + m16;
                out[(size_t)i * Op + j] = f2bf(acc[rt][ct][r4]);
            }
        }
    }
}

// ---------------- GRU gates + relu, fast transcendentals, 8 ch/thread ----------------
__global__ __launch_bounds__(256) void gru_gates(const unsigned short* __restrict__ gi,
                                                 const float* __restrict__ bc,
                                                 float* __restrict__ h,
                                                 unsigned short* __restrict__ cat) {
    int idx = blockIdx.x * 256 + threadIdx.x;   // N*16
    if (idx >= N_NODES * 16) return;
    int i = idx >> 4;
    int c8 = (idx & 15) * 8;
    size_t base = (size_t)i * 512;
    bf16x8 vr = *(const bf16x8*)(gi + base + c8);
    bf16x8 vz = *(const bf16x8*)(gi + base + 128 + c8);
    bf16x8 vn = *(const bf16x8*)(gi + base + 256 + c8);
    bf16x8 vh = *(const bf16x8*)(gi + base + 384 + c8);
    float4 ho0 = *(const float4*)(h + (size_t)i * 128 + c8);
    float4 ho1 = *(const float4*)(h + (size_t)i * 128 + c8 + 4);
    float hold[8] = {ho0.x, ho0.y, ho0.z, ho0.w, ho1.x, ho1.y, ho1.z, ho1.w};
    float outv[8];
    #pragma unroll
    for (int q = 0; q < 8; ++q) {
        int cc = c8 + q;
        float r_pre = bf2f((unsigned short)vr[q]) + bc[cc];
        float z_pre = bf2f((unsigned short)vz[q]) + bc[128 + cc];
        float n_i   = bf2f((unsigned short)vn[q]) + bc[256 + cc];
        float n_h   = bf2f((unsigned short)vh[q]) + bc[384 + cc];
        float r = 1.f / (1.f + __expf(-r_pre));
        float z = 1.f / (1.f + __expf(-z_pre));
        float a = n_i + r * n_h;
        a = fminf(fmaxf(a, -20.f), 20.f);
        float t = __expf(2.f * a);
        float n = (t - 1.f) / (t + 1.f);
        float o = (1.f - z) * n + z * hold[q];
        outv[q] = o > 0.f ? o : 0.f;
    }
    float4 o0 = {outv[0], outv[1], outv[2], outv[3]};
    float4 o1 = {outv[4], outv[5], outv[6], outv[7]};
    *(float4*)(h + (size_t)i * 128 + c8) = o0;
    *(float4*)(h + (size_t)i * 128 + c8 + 4) = o1;
    bf16x8 hb;
    #pragma unroll
    for (int q = 0; q < 8; ++q) hb[q] = (short)f2bf(outv[q]);
    *(bf16x8*)(cat + (size_t)i * 256 + 128 + c8) = hb;
}

// ---------------- mean pool over sorted batch ----------------
__global__ __launch_bounds__(128) void pool_sorted(const float* __restrict__ h,
                                                   const int* __restrict__ batch,
                                                   float* __restrict__ hg) {
    int g = blockIdx.x;
    int c = threadIdx.x;
    int lo = 0, hi = N_NODES;
    while (lo < hi) { int mid = (lo + hi) >> 1; if (batch[mid] < g) lo = mid + 1; else hi = mid; }
    int start = lo;
    lo = start; hi = N_NODES;
    while (lo < hi) { int mid = (lo + hi) >> 1; if (batch[mid] < g + 1) lo = mid + 1; else hi = mid; }
    int end = lo;
    float s = 0.f;
    for (int i = start; i < end; ++i) s += h[(size_t)i * D + c];
    float cnt = (float)(end - start);
    hg[(size_t)g * D + c] = s / fmaxf(cnt, 1.f);
}

// ---------------- fc1 + elu ----------------
__global__ __launch_bounds__(128) void fc1_elu(const float* __restrict__ hg,
                                               const float* __restrict__ w,
                                               const float* __restrict__ b,
                                               float* __restrict__ z) {
    __shared__ float row[128];
    int g = blockIdx.x;
    int j = threadIdx.x;
    row[j] = hg[(size_t)g * 128 + j];
    __syncthreads();
    float acc = b[j];
    const float* wr = w + (size_t)j * 128;
    #pragma unroll 4
    for (int k = 0; k < 128; ++k) acc += row[k] * wr[k];
    z[(size_t)g * 128 + j] = acc > 0.f ? acc : (expf(acc) - 1.f);
}

// ---------------- fc2 ----------------
__global__ __launch_bounds__(64) void fc2_k(const float* __restrict__ z,
                                            const float* __restrict__ w,
                                            const float* __restrict__ b,
                                            float* __restrict__ logits) {
    __shared__ float row[128];
    int g = blockIdx.x;
    int t = threadIdx.x;
    row[t] = z[(size_t)g * 128 + t];
    row[t + 64] = z[(size_t)g * 128 + 64 + t];
    __syncthreads();
    if (t < N_CLASSES) {
        float acc = b[t];
        const float* wr = w + (size_t)t * 128;
        #pragma unroll 4
        for (int k = 0; k < 128; ++k) acc += row[k] * wr[k];
        logits[(size_t)g * N_CLASSES + t] = acc;
    }
}

// ---------------- log_softmax over axis 0 ----------------
__global__ __launch_bounds__(512) void logsoftmax_axis0(const float* __restrict__ logits,
                                                        float* __restrict__ out) {
    __shared__ float red[512];
    int c = blockIdx.x;
    int g = threadIdx.x;
    float x = logits[(size_t)g * N_CLASSES + c];
    red[g] = x;
    __syncthreads();
    for (int s = 256; s > 0; s >>= 1) {
        if (g < s) red[g] = fmaxf(red[g], red[g + s]);
        __syncthreads();
    }
    float mx = red[0];
    __syncthreads();
    red[g] = expf(x - mx);
    __syncthreads();
    for (int s = 256; s > 0; s >>= 1) {
        if (g < s) red[g] += red[g + s];
        __syncthreads();
    }
    float lse = mx + logf(red[0]);
    out[(size_t)g * N_CLASSES + c] = x - lse;
}

// ---------------- launch ----------------
extern "C" void kernel_launch(void* const* d_in, const int* in_sizes, int n_in,
                              void* d_out, int out_size, void* d_ws, size_t ws_size,
                              hipStream_t stream) {
    const float* h_in   = (const float*)d_in[0];
    const int*   eidx   = (const int*)d_in[1];
    const int*   batch  = (const int*)d_in[3];
    const float* Ws     = (const float*)d_in[4];
    const float* W_ih   = (const float*)d_in[5];
    const float* W_hh   = (const float*)d_in[6];
    const float* b_ih   = (const float*)d_in[7];
    const float* b_hh   = (const float*)d_in[8];
    const float* fc1_w  = (const float*)d_in[9];
    const float* fc1_b  = (const float*)d_in[10];
    const float* fc2_w  = (const float*)d_in[11];
    const float* fc2_b  = (const float*)d_in[12];
    float* out = (float*)d_out;

    char* ws = (char*)d_ws;
    size_t off = 0;
    auto alloc = [&](size_t bytes) {
        void* p = ws + off;
        off += (bytes + 255) & ~(size_t)255;
        return p;
    };
    float* h             = (float*)alloc((size_t)N_NODES * D * 4);
    unsigned short* cat  = (unsigned short*)alloc((size_t)N_NODES * 256 * 2);  // [agg | h] bf16
    unsigned short* gi   = (unsigned short*)alloc((size_t)N_NODES * 512 * 2);  // gemm out bf16
    unsigned short* Ws_bf  = (unsigned short*)alloc((size_t)N_LAYERS * D * D * 2);
    unsigned short* Wih_bf = (unsigned short*)alloc((size_t)N_LAYERS * 3 * D * D * 2);
    unsigned short* Whh_bf = (unsigned short*)alloc((size_t)N_LAYERS * 3 * D * D * 2);
    unsigned short* Wp_bf  = (unsigned short*)alloc((size_t)N_LAYERS * 3 * D * D * 2);  // Wih @ Ws^T
    unsigned short* Bcat   = (unsigned short*)alloc((size_t)N_LAYERS * 512 * 256 * 2);
    float* bc   = (float*)alloc((size_t)N_LAYERS * 512 * 4);
    float* hg   = (float*)alloc((size_t)N_GRAPHS * D * 4);
    float* zb   = (float*)alloc((size_t)N_GRAPHS * D * 4);
    float* lgts = (float*)alloc((size_t)N_GRAPHS * N_CLASSES * 4);
    int* deg     = (int*)alloc((size_t)N_NODES * 4);
    int* row_ptr = (int*)alloc((size_t)(N_NODES + 1) * 4);
    int* pos     = (int*)alloc((size_t)N_NODES * 4);
    int* csr_src = (int*)alloc((size_t)N_EDGES * 4);
    int* bsum    = (int*)alloc((size_t)NBLK_SCAN * 4);
    int* boff    = (int*)alloc((size_t)NBLK_SCAN * 4);

    const int* src = eidx;
    const int* dst = eidx + N_EDGES;

    convert_h<<<(N_NODES * D + 255) / 256, 256, 0, stream>>>(h_in, h, cat);
    convert_weights<<<(N_LAYERS * 3 * D * D + 255) / 256, 256, 0, stream>>>(
        Ws, W_ih, W_hh, Ws_bf, Wih_bf, Whh_bf);
    combine_bias<<<(N_LAYERS * 512 + 255) / 256, 256, 0, stream>>>(b_ih, b_hh, bc);

    // W'_l = Wih_l @ Ws_l^T, batched over layers via grid.z
    gemm_bf16<<<dim3(3, 1, N_LAYERS), 256, 0, stream>>>(
        Wih_bf, 128, Ws_bf, 128, Wp_bf, 128, 384, 128,
        (size_t)384 * 128, (size_t)128 * 128, (size_t)384 * 128);
    build_bcat<<<(N_LAYERS * 512 * 256 + 255) / 256, 256, 0, stream>>>(Wp_bf, Whh_bf, Bcat);

    // CSR build (edges static) — distributed scan
    fill_zero4<<<(N_NODES / 4 + 255) / 256, 256, 0, stream>>>((float4*)deg, N_NODES / 4);
    hist_dst<<<(N_EDGES + 255) / 256, 256, 0, stream>>>(dst, deg);
    block_sum<<<NBLK_SCAN, 256, 0, stream>>>(deg, bsum);
    scan_partials<<<1, 256, 0, stream>>>(bsum, boff, row_ptr);
    scan_final<<<NBLK_SCAN, 256, 0, stream>>>(deg, boff, row_ptr, pos);
    fill_csr<<<(N_EDGES + 255) / 256, 256, 0, stream>>>(src, dst, pos, csr_src);

    const int mtiles = (N_NODES + 127) / 128;   // 391
    for (int l = 0; l < N_LAYERS; ++l) {
        // cat[:,0:128] = gather of cat[:,128:256]  (agg_h)
        gather_agg<<<(N_NODES + 15) / 16, 256, 0, stream>>>(cat, row_ptr, csr_src);
        // gi = cat @ Bcat_l^T   (K=256, N=512)
        gemm_bf16<<<dim3(mtiles, 4, 1), 256, 0, stream>>>(
            cat, 256, Bcat + (size_t)l * 512 * 256, 256, gi, 512, N_NODES, 256, 0, 0, 0);
        // gates + relu -> h fp32, cat[:,128:256] bf16
        gru_gates<<<(N_NODES * 16 + 255) / 256, 256, 0, stream>>>(
            gi, bc + (size_t)l * 512, h, cat);
    }

    pool_sorted<<<N_GRAPHS, 128, 0, stream>>>(h, batch, hg);
    fc1_elu<<<N_GRAPHS, 128, 0, stream>>>(hg, fc1_w, fc1_b, zb);
    fc2_k<<<N_GRAPHS, 64, 0, stream>>>(zb, fc2_w, fc2_b, lgts);
    logsoftmax_axis0<<<N_CLASSES, 512, 0, stream>>>(lgts, out);
}

// Round 7
// 504.865 us; speedup vs baseline: 11.4204x; 1.0860x over previous
//
#include <hip/hip_runtime.h>
#include <math.h>

#define N_NODES 50000
#define N_EDGES 600000
#define D 128
#define N_GRAPHS 512
#define N_CLASSES 10
#define N_LAYERS 4
#define NBLK_SCAN 196   // ceil(50000/256)

typedef __attribute__((ext_vector_type(8))) short bf16x8;
typedef __attribute__((ext_vector_type(4))) float f32x4;

__device__ inline unsigned short f2bf(float f) {
    union { float f; unsigned int u; } v; v.f = f;
    unsigned int r = (v.u + 0x7fffu + ((v.u >> 16) & 1u)) >> 16;
    return (unsigned short)r;
}
__device__ inline float bf2f(unsigned short u) {
    union { unsigned int u; float f; } v; v.u = ((unsigned int)u) << 16;
    return v.f;
}

// ---------------- zero fill ----------------
__global__ __launch_bounds__(256) void fill_zero4(float4* p, int n4) {
    int i = blockIdx.x * 256 + threadIdx.x;
    if (i < n4) p[i] = make_float4(0.f, 0.f, 0.f, 0.f);
}

// ---------------- fused init: h copy/mirror + weight bf16 + combined bias ----------------
// bc layout [L][512]: j<128: bih_r+bhh_r ; 128..256: bih_z+bhh_z ; 256..384: bih_n ; 384..512: bhh_n
__global__ __launch_bounds__(256) void init_all(const float* __restrict__ h_in,
                                                const float* __restrict__ Ws,
                                                const float* __restrict__ Wih,
                                                const float* __restrict__ Whh,
                                                const float* __restrict__ bih,
                                                const float* __restrict__ bhh,
                                                float* __restrict__ h,
                                                unsigned short* __restrict__ cat,
                                                unsigned short* __restrict__ Ws_bf,
                                                unsigned short* __restrict__ Wih_bf,
                                                unsigned short* __restrict__ Whh_bf,
                                                float* __restrict__ bc) {
    int idx = blockIdx.x * 256 + threadIdx.x;
    if (idx < N_NODES * D) {
        int i = idx >> 7;
        int c = idx & 127;
        float v = h_in[idx];
        h[idx] = v;
        cat[(size_t)i * 256 + 128 + c] = f2bf(v);
    }
    if (idx < N_LAYERS * D * D) Ws_bf[idx] = f2bf(Ws[idx]);
    if (idx < N_LAYERS * 3 * D * D) {
        Wih_bf[idx] = f2bf(Wih[idx]);
        Whh_bf[idx] = f2bf(Whh[idx]);
    }
    if (idx < N_LAYERS * 512) {
        int l = idx >> 9;
        int j = idx & 511;
        const float* bi = bih + (size_t)l * 384;
        const float* bh = bhh + (size_t)l * 384;
        float v;
        if (j < 256) v = bi[j] + bh[j];
        else if (j < 384) v = bi[j];
        else v = bh[j - 128];
        bc[idx] = v;
    }
}

// ---------------- build B_cat2[l][512][256], gate-interleaved columns ----------------
// j' = ch*4 + gate (gate: 0=r, 1=z, 2=i_n, 3=h_n); maps to old j = gate*128 + ch.
// old j<256:  k<128 -> W'[l][j][k], k>=128 -> Whh[l][j][k-128]
// old 256..384 (i_n): k<128 -> W'[l][j][k], else 0
// old 384..512 (h_n): k>=128 -> Whh[l][j-128][k-128], else 0
__global__ __launch_bounds__(256) void build_bcat(const unsigned short* __restrict__ Wp,
                                                  const unsigned short* __restrict__ Whh,
                                                  unsigned short* __restrict__ Bcat) {
    int idx = blockIdx.x * 256 + threadIdx.x;   // L*512*256
    if (idx >= N_LAYERS * 512 * 256) return;
    int l = idx >> 17;
    int rem = idx & 131071;
    int jp = rem >> 8;
    int k = rem & 255;
    int gate = jp & 3;
    int ch = jp >> 2;
    int j = gate * 128 + ch;
    unsigned short v = 0;
    if (j < 256) {
        v = (k < 128) ? Wp[((size_t)l * 384 + j) * 128 + k]
                      : Whh[((size_t)l * 384 + j) * 128 + (k - 128)];
    } else if (j < 384) {
        v = (k < 128) ? Wp[((size_t)l * 384 + j) * 128 + k] : (unsigned short)0;
    } else {
        v = (k >= 128) ? Whh[((size_t)l * 384 + (j - 128)) * 128 + (k - 128)] : (unsigned short)0;
    }
    Bcat[idx] = v;
}

// ---------------- CSR build ----------------
__global__ __launch_bounds__(256) void hist_dst(const int* __restrict__ dst,
                                                int* __restrict__ deg) {
    int e = blockIdx.x * 256 + threadIdx.x;
    if (e < N_EDGES) atomicAdd(&deg[dst[e]], 1);
}

__global__ __launch_bounds__(256) void block_sum(const int* __restrict__ deg,
                                                 int* __restrict__ bsum) {
    __shared__ int s[256];
    int t = threadIdx.x;
    int i = blockIdx.x * 256 + t;
    s[t] = (i < N_NODES) ? deg[i] : 0;
    __syncthreads();
    for (int o = 128; o > 0; o >>= 1) {
        if (t < o) s[t] += s[t + o];
        __syncthreads();
    }
    if (t == 0) bsum[blockIdx.x] = s[0];
}

__global__ __launch_bounds__(256) void scan_partials(const int* __restrict__ bsum,
                                                     int* __restrict__ boff,
                                                     int* __restrict__ row_ptr) {
    __shared__ int s[256];
    int t = threadIdx.x;
    int v = (t < NBLK_SCAN) ? bsum[t] : 0;
    s[t] = v;
    __syncthreads();
    for (int o = 1; o < 256; o <<= 1) {
        int x = (t >= o) ? s[t - o] : 0;
        __syncthreads();
        s[t] += x;
        __syncthreads();
    }
    if (t < NBLK_SCAN) boff[t] = s[t] - v;   // exclusive
    if (t == 255) row_ptr[N_NODES] = s[255];
}

__global__ __launch_bounds__(256) void scan_final(const int* __restrict__ deg,
                                                  const int* __restrict__ boff,
                                                  int* __restrict__ row_ptr,
                                                  int* __restrict__ pos) {
    __shared__ int s[256];
    int t = threadIdx.x;
    int i = blockIdx.x * 256 + t;
    int v = (i < N_NODES) ? deg[i] : 0;
    s[t] = v;
    __syncthreads();
    for (int o = 1; o < 256; o <<= 1) {
        int x = (t >= o) ? s[t - o] : 0;
        __syncthreads();
        s[t] += x;
        __syncthreads();
    }
    int excl = s[t] - v + boff[blockIdx.x];
    if (i < N_NODES) {
        row_ptr[i] = excl;
        pos[i] = excl;
    }
}

__global__ __launch_bounds__(256) void fill_csr(const int* __restrict__ src,
                                                const int* __restrict__ dst,
                                                int* __restrict__ pos,
                                                int* __restrict__ csr_src) {
    int e = blockIdx.x * 256 + threadIdx.x;
    if (e >= N_EDGES) return;
    int p = atomicAdd(&pos[dst[e]], 1);
    csr_src[p] = src[e];
}

// ---------------- gather: cat[n, 0:128] = sum_{e:dst=n} cat[src[e], 128:256] ----------------
__global__ __launch_bounds__(256) void gather_agg(unsigned short* __restrict__ cat,
                                                  const int* __restrict__ row_ptr,
                                                  const int* __restrict__ csr_src) {
    int t = threadIdx.x;
    int node = blockIdx.x * 16 + (t >> 4);
    int c8 = (t & 15) * 8;
    if (node >= N_NODES) return;
    int b = row_ptr[node];
    int e2 = row_ptr[node + 1];
    float acc0[8] = {}, acc1[8] = {};
    int e = b;
    for (; e + 2 <= e2; e += 2) {
        int s0 = csr_src[e];
        int s1 = csr_src[e + 1];
        bf16x8 v0 = *(const bf16x8*)(cat + (size_t)s0 * 256 + 128 + c8);
        bf16x8 v1 = *(const bf16x8*)(cat + (size_t)s1 * 256 + 128 + c8);
        #pragma unroll
        for (int j = 0; j < 8; ++j) {
            acc0[j] += bf2f((unsigned short)v0[j]);
            acc1[j] += bf2f((unsigned short)v1[j]);
        }
    }
    if (e < e2) {
        int s0 = csr_src[e];
        bf16x8 v0 = *(const bf16x8*)(cat + (size_t)s0 * 256 + 128 + c8);
        #pragma unroll
        for (int j = 0; j < 8; ++j) acc0[j] += bf2f((unsigned short)v0[j]);
    }
    bf16x8 ov;
    #pragma unroll
    for (int j = 0; j < 8; ++j) ov[j] = (short)f2bf(acc0[j] + acc1[j]);
    *(bf16x8*)(cat + (size_t)node * 256 + c8) = ov;
}

// ---------------- generic bf16 MFMA GEMM (used for the tiny W' precompute) ----------------
__global__ __launch_bounds__(256) void gemm_bf16(const unsigned short* __restrict__ A, int Ap,
                                                 const unsigned short* __restrict__ W, int Wp,
                                                 unsigned short* __restrict__ out, int Op,
                                                 int M, int Kd,
                                                 size_t lsA, size_t lsW, size_t lsO) {
    A += (size_t)blockIdx.z * lsA;
    W += (size_t)blockIdx.z * lsW;
    out += (size_t)blockIdx.z * lsO;

    __shared__ unsigned short As[128 * 72];
    __shared__ unsigned short Bs[128 * 72];

    const int tid = threadIdx.x;
    const int i0 = blockIdx.x * 128;
    const int j0 = blockIdx.y * 128;

    const int wave = tid >> 6;
    const int lane = tid & 63;
    const int m16 = lane & 15;
    const int quad = lane >> 4;
    const int mr = (wave & 1) * 64;
    const int nc = (wave >> 1) * 64;

    f32x4 acc[4][4];
    #pragma unroll
    for (int a = 0; a < 4; ++a)
        #pragma unroll
        for (int b = 0; b < 4; ++b)
            acc[a][b] = (f32x4){0.f, 0.f, 0.f, 0.f};

    const int r0 = tid >> 3;
    const int kk = (tid & 7) * 8;

    for (int kc = 0; kc < Kd; kc += 64) {
        if (kc) __syncthreads();
        #pragma unroll
        for (int it = 0; it < 4; ++it) {
            int r = r0 + it * 32;
            int gi_ = i0 + r;
            bf16x8 av = {0, 0, 0, 0, 0, 0, 0, 0};
            if (gi_ < M) av = *(const bf16x8*)(A + (size_t)gi_ * Ap + kc + kk);
            *(bf16x8*)&As[r * 72 + kk] = av;
            *(bf16x8*)&Bs[r * 72 + kk] = *(const bf16x8*)(W + (size_t)(j0 + r) * Wp + kc + kk);
        }
        __syncthreads();

        #pragma unroll
        for (int ks = 0; ks < 64; ks += 32) {
            bf16x8 af[4], bf_[4];
            #pragma unroll
            for (int rt = 0; rt < 4; ++rt)
                af[rt] = *(const bf16x8*)&As[(mr + rt * 16 + m16) * 72 + ks + quad * 8];
            #pragma unroll
            for (int ct = 0; ct < 4; ++ct)
                bf_[ct] = *(const bf16x8*)&Bs[(nc + ct * 16 + m16) * 72 + ks + quad * 8];
            #pragma unroll
            for (int rt = 0; rt < 4; ++rt)
                #pragma unroll
                for (int ct = 0; ct < 4; ++ct)
                    acc[rt][ct] = __builtin_amdgcn_mfma_f32_16x16x32_bf16(
                        af[rt], bf_[ct], acc[rt][ct], 0, 0, 0);
        }
    }

    #pragma unroll
    for (int rt = 0; rt < 4; ++rt) {
        #pragma unroll
        for (int r4 = 0; r4 < 4; ++r4) {
            int i = i0 + mr + rt * 16 + quad * 4 + r4;
            if (i >= M) continue;
            #pragma unroll
            for (int ct = 0; ct < 4; ++ct) {
                int j = j0 + nc + ct * 16 + m16;
                out[(size_t)i * Op + j] = f2bf(acc[rt][ct][r4]);
            }
        }
    }
}

// ---------------- fused GEMM + GRU gates ----------------
// A = cat [N_NODES][256] bf16, W = Bcat2 layer [512][256] bf16 (gate-interleaved cols).
// Block: 128 rows x 128 j' (= 32 channels x 4 gates). Epilogue transposes acc through
// LDS (reusing As) and applies sigmoid/tanh gates; writes h fp32 + cat bf16 mirror.
__global__ __launch_bounds__(256) void gemm_gru(const unsigned short* __restrict__ A,
                                                const unsigned short* __restrict__ W,
                                                const float* __restrict__ bc,
                                                float* __restrict__ h,
                                                unsigned short* __restrict__ cat) {
    __shared__ unsigned short As[128 * 72];
    __shared__ unsigned short Bs[128 * 72];
    float* Ls = (float*)As;   // 32*132*4 = 16896 B <= 18432 B, reused after K-loop

    const int tid = threadIdx.x;
    const int i0 = blockIdx.x * 128;
    const int j0 = blockIdx.y * 128;
    const int ch_base = blockIdx.y * 32;

    const int wave = tid >> 6;
    const int lane = tid & 63;
    const int m16 = lane & 15;
    const int quad = lane >> 4;
    const int mr = (wave & 1) * 64;
    const int nc = (wave >> 1) * 64;

    f32x4 acc[4][4];
    #pragma unroll
    for (int a = 0; a < 4; ++a)
        #pragma unroll
        for (int b = 0; b < 4; ++b)
            acc[a][b] = (f32x4){0.f, 0.f, 0.f, 0.f};

    const int r0 = tid >> 3;
    const int kk = (tid & 7) * 8;

    for (int kc = 0; kc < 256; kc += 64) {
        if (kc) __syncthreads();
        #pragma unroll
        for (int it = 0; it < 4; ++it) {
            int r = r0 + it * 32;
            int gi_ = i0 + r;
            bf16x8 av = {0, 0, 0, 0, 0, 0, 0, 0};
            if (gi_ < N_NODES) av = *(const bf16x8*)(A + (size_t)gi_ * 256 + kc + kk);
            *(bf16x8*)&As[r * 72 + kk] = av;
            *(bf16x8*)&Bs[r * 72 + kk] = *(const bf16x8*)(W + (size_t)(j0 + r) * 256 + kc + kk);
        }
        __syncthreads();

        #pragma unroll
        for (int ks = 0; ks < 64; ks += 32) {
            bf16x8 af[4], bf_[4];
            #pragma unroll
            for (int rt = 0; rt < 4; ++rt)
                af[rt] = *(const bf16x8*)&As[(mr + rt * 16 + m16) * 72 + ks + quad * 8];
            #pragma unroll
            for (int ct = 0; ct < 4; ++ct)
                bf_[ct] = *(const bf16x8*)&Bs[(nc + ct * 16 + m16) * 72 + ks + quad * 8];
            #pragma unroll
            for (int rt = 0; rt < 4; ++rt)
                #pragma unroll
                for (int ct = 0; ct < 4; ++ct)
                    acc[rt][ct] = __builtin_amdgcn_mfma_f32_16x16x32_bf16(
                        af[rt], bf_[ct], acc[rt][ct], 0, 0, 0);
        }
    }

    // epilogue: 4 chunks of 32 rows through LDS, then gates
    const int lr_w = (wave & 1) * 16;          // write-side local row base
    const int lrr = tid >> 3;                  // read-side local row 0..31
    const int c4 = (tid & 7) * 4;              // read-side local channel base (0..28)
    #pragma unroll
    for (int rt = 0; rt < 4; ++rt) {
        __syncthreads();   // previous chunk fully read (or K-loop LDS reads done)
        #pragma unroll
        for (int ct = 0; ct < 4; ++ct)
            #pragma unroll
            for (int r4 = 0; r4 < 4; ++r4)
                Ls[(lr_w + quad * 4 + r4) * 132 + nc + ct * 16 + m16] = acc[rt][ct][r4];
        __syncthreads();

        int gr = i0 + (lrr >> 4) * 64 + rt * 16 + (lrr & 15);
        if (gr < N_NODES) {
            float4 hold4 = *(const float4*)(h + (size_t)gr * 128 + ch_base + c4);
            float hold[4] = {hold4.x, hold4.y, hold4.z, hold4.w};
            float ov[4];
            #pragma unroll
            for (int q = 0; q < 4; ++q) {
                int ch = c4 + q;
                int gch = ch_base + ch;
                float rv  = Ls[lrr * 132 + ch * 4 + 0] + bc[gch];
                float zv  = Ls[lrr * 132 + ch * 4 + 1] + bc[128 + gch];
                float niv = Ls[lrr * 132 + ch * 4 + 2] + bc[256 + gch];
                float nhv = Ls[lrr * 132 + ch * 4 + 3] + bc[384 + gch];
                float r = 1.f / (1.f + __expf(-rv));
                float z = 1.f / (1.f + __expf(-zv));
                float a = niv + r * nhv;
                a = fminf(fmaxf(a, -20.f), 20.f);
                float t2 = __expf(2.f * a);
                float n = (t2 - 1.f) / (t2 + 1.f);
                float o = (1.f - z) * n + z * hold[q];
                ov[q] = o > 0.f ? o : 0.f;
            }
            *(float4*)(h + (size_t)gr * 128 + ch_base + c4) = make_float4(ov[0], ov[1], ov[2], ov[3]);
            ushort4 hb4;
            hb4.x = f2bf(ov[0]); hb4.y = f2bf(ov[1]); hb4.z = f2bf(ov[2]); hb4.w = f2bf(ov[3]);
            *(ushort4*)(cat + (size_t)gr * 256 + 128 + ch_base + c4) = hb4;
        }
    }
}

// ---------------- mean pool over sorted batch ----------------
__global__ __launch_bounds__(128) void pool_sorted(const float* __restrict__ h,
                                                   const int* __restrict__ batch,
                                                   float* __restrict__ hg) {
    int g = blockIdx.x;
    int c = threadIdx.x;
    int lo = 0, hi = N_NODES;
    while (lo < hi) { int mid = (lo + hi) >> 1; if (batch[mid] < g) lo = mid + 1; else hi = mid; }
    int start = lo;
    lo = start; hi = N_NODES;
    while (lo < hi) { int mid = (lo + hi) >> 1; if (batch[mid] < g + 1) lo = mid + 1; else hi = mid; }
    int end = lo;
    float s = 0.f;
    for (int i = start; i < end; ++i) s += h[(size_t)i * D + c];
    float cnt = (float)(end - start);
    hg[(size_t)g * D + c] = s / fmaxf(cnt, 1.f);
}

// ---------------- fc1 + elu ----------------
__global__ __launch_bounds__(128) void fc1_elu(const float* __restrict__ hg,
                                               const float* __restrict__ w,
                                               const float* __restrict__ b,
                                               float* __restrict__ z) {
    __shared__ float row[128];
    int g = blockIdx.x;
    int j = threadIdx.x;
    row[j] = hg[(size_t)g * 128 + j];
    __syncthreads();
    float acc = b[j];
    const float* wr = w + (size_t)j * 128;
    #pragma unroll 4
    for (int k = 0; k < 128; ++k) acc += row[k] * wr[k];
    z[(size_t)g * 128 + j] = acc > 0.f ? acc : (expf(acc) - 1.f);
}

// ---------------- fc2 ----------------
__global__ __launch_bounds__(64) void fc2_k(const float* __restrict__ z,
                                            const float* __restrict__ w,
                                            const float* __restrict__ b,
                                            float* __restrict__ logits) {
    __shared__ float row[128];
    int g = blockIdx.x;
    int t = threadIdx.x;
    row[t] = z[(size_t)g * 128 + t];
    row[t + 64] = z[(size_t)g * 128 + 64 + t];
    __syncthreads();
    if (t < N_CLASSES) {
        float acc = b[t];
        const float* wr = w + (size_t)t * 128;
        #pragma unroll 4
        for (int k = 0; k < 128; ++k) acc += row[k] * wr[k];
        logits[(size_t)g * N_CLASSES + t] = acc;
    }
}

// ---------------- log_softmax over axis 0 ----------------
__global__ __launch_bounds__(512) void logsoftmax_axis0(const float* __restrict__ logits,
                                                        float* __restrict__ out) {
    __shared__ float red[512];
    int c = blockIdx.x;
    int g = threadIdx.x;
    float x = logits[(size_t)g * N_CLASSES + c];
    red[g] = x;
    __syncthreads();
    for (int s = 256; s > 0; s >>= 1) {
        if (g < s) red[g] = fmaxf(red[g], red[g + s]);
        __syncthreads();
    }
    float mx = red[0];
    __syncthreads();
    red[g] = expf(x - mx);
    __syncthreads();
    for (int s = 256; s > 0; s >>= 1) {
        if (g < s) red[g] += red[g + s];
        __syncthreads();
    }
    float lse = mx + logf(red[0]);
    out[(size_t)g * N_CLASSES + c] = x - lse;
}

// ---------------- launch ----------------
extern "C" void kernel_launch(void* const* d_in, const int* in_sizes, int n_in,
                              void* d_out, int out_size, void* d_ws, size_t ws_size,
                              hipStream_t stream) {
    const float* h_in   = (const float*)d_in[0];
    const int*   eidx   = (const int*)d_in[1];
    const int*   batch  = (const int*)d_in[3];
    const float* Ws     = (const float*)d_in[4];
    const float* W_ih   = (const float*)d_in[5];
    const float* W_hh   = (const float*)d_in[6];
    const float* b_ih   = (const float*)d_in[7];
    const float* b_hh   = (const float*)d_in[8];
    const float* fc1_w  = (const float*)d_in[9];
    const float* fc1_b  = (const float*)d_in[10];
    const float* fc2_w  = (const float*)d_in[11];
    const float* fc2_b  = (const float*)d_in[12];
    float* out = (float*)d_out;

    char* ws = (char*)d_ws;
    size_t off = 0;
    auto alloc = [&](size_t bytes) {
        void* p = ws + off;
        off += (bytes + 255) & ~(size_t)255;
        return p;
    };
    float* h             = (float*)alloc((size_t)N_NODES * D * 4);
    unsigned short* cat  = (unsigned short*)alloc((size_t)N_NODES * 256 * 2);  // [agg | h] bf16
    unsigned short* Ws_bf  = (unsigned short*)alloc((size_t)N_LAYERS * D * D * 2);
    unsigned short* Wih_bf = (unsigned short*)alloc((size_t)N_LAYERS * 3 * D * D * 2);
    unsigned short* Whh_bf = (unsigned short*)alloc((size_t)N_LAYERS * 3 * D * D * 2);
    unsigned short* Wp_bf  = (unsigned short*)alloc((size_t)N_LAYERS * 3 * D * D * 2);  // Wih @ Ws^T
    unsigned short* Bcat   = (unsigned short*)alloc((size_t)N_LAYERS * 512 * 256 * 2);
    float* bc   = (float*)alloc((size_t)N_LAYERS * 512 * 4);
    float* hg   = (float*)alloc((size_t)N_GRAPHS * D * 4);
    float* zb   = (float*)alloc((size_t)N_GRAPHS * D * 4);
    float* lgts = (float*)alloc((size_t)N_GRAPHS * N_CLASSES * 4);
    int* deg     = (int*)alloc((size_t)N_NODES * 4);
    int* row_ptr = (int*)alloc((size_t)(N_NODES + 1) * 4);
    int* pos     = (int*)alloc((size_t)N_NODES * 4);
    int* csr_src = (int*)alloc((size_t)N_EDGES * 4);
    int* bsum    = (int*)alloc((size_t)NBLK_SCAN * 4);
    int* boff    = (int*)alloc((size_t)NBLK_SCAN * 4);

    const int* src = eidx;
    const int* dst = eidx + N_EDGES;

    init_all<<<(N_NODES * D + 255) / 256, 256, 0, stream>>>(
        h_in, Ws, W_ih, W_hh, b_ih, b_hh, h, cat, Ws_bf, Wih_bf, Whh_bf, bc);

    // W'_l = Wih_l @ Ws_l^T, batched over layers via grid.z
    gemm_bf16<<<dim3(3, 1, N_LAYERS), 256, 0, stream>>>(
        Wih_bf, 128, Ws_bf, 128, Wp_bf, 128, 384, 128,
        (size_t)384 * 128, (size_t)128 * 128, (size_t)384 * 128);
    build_bcat<<<(N_LAYERS * 512 * 256 + 255) / 256, 256, 0, stream>>>(Wp_bf, Whh_bf, Bcat);

    // CSR build (edges static) — distributed scan
    fill_zero4<<<(N_NODES / 4 + 255) / 256, 256, 0, stream>>>((float4*)deg, N_NODES / 4);
    hist_dst<<<(N_EDGES + 255) / 256, 256, 0, stream>>>(dst, deg);
    block_sum<<<NBLK_SCAN, 256, 0, stream>>>(deg, bsum);
    scan_partials<<<1, 256, 0, stream>>>(bsum, boff, row_ptr);
    scan_final<<<NBLK_SCAN, 256, 0, stream>>>(deg, boff, row_ptr, pos);
    fill_csr<<<(N_EDGES + 255) / 256, 256, 0, stream>>>(src, dst, pos, csr_src);

    const int mtiles = (N_NODES + 127) / 128;   // 391
    for (int l = 0; l < N_LAYERS; ++l) {
        // cat[:,0:128] = gather of cat[:,128:256]  (agg_h)
        gather_agg<<<(N_NODES + 15) / 16, 256, 0, stream>>>(cat, row_ptr, csr_src);
        // fused: gates(cat @ Bcat2_l^T) -> h fp32 + cat[:,128:256] bf16
        gemm_gru<<<dim3(mtiles, 4), 256, 0, stream>>>(
            cat, Bcat + (size_t)l * 512 * 256, bc + (size_t)l * 512, h, cat);
    }

    pool_sorted<<<N_GRAPHS, 128, 0, stream>>>(h, batch, hg);
    fc1_elu<<<N_GRAPHS, 128, 0, stream>>>(hg, fc1_w, fc1_b, zb);
    fc2_k<<<N_GRAPHS, 64, 0, stream>>>(zb, fc2_w, fc2_b, lgts);
    logsoftmax_axis0<<<N_CLASSES, 512, 0, stream>>>(lgts, out);
}